// Round 6
// baseline (683.990 us; speedup 1.0000x reference)
//
#include <hip/hip_runtime.h>
#include <hip/hip_bf16.h>
#include <math.h>

#define HID 64

// ---- bf16 pack/unpack (RNE) ----
__device__ __forceinline__ unsigned int bf16r(float f) {
    unsigned int u = __float_as_uint(f);
    return (u + 0x7fffu + ((u >> 16) & 1u)) >> 16;
}
__device__ __forceinline__ unsigned int pack2(float a, float b) {
    return bf16r(a) | (bf16r(b) << 16);
}
__device__ __forceinline__ float lo2f(unsigned int u) { return __uint_as_float(u << 16); }
__device__ __forceinline__ float hi2f(unsigned int u) { return __uint_as_float(u & 0xffff0000u); }

// chunked bf16 feature tables: [4 chunks][N][8 u32]; chunk = pc>>3
__device__ __forceinline__ unsigned int chread(const unsigned int* buf, int N, int gc, int pc) {
    return buf[(size_t)(pc >> 3) * ((size_t)N * 8) + (size_t)gc * 8 + (pc & 7)];
}

// ---------------- histogram (x4 vectorized) ----------------
__global__ void hist_kernel(const int* __restrict__ ei, int E,
                            float* __restrict__ degS, int* __restrict__ cnt) {
    int e = (blockIdx.x * blockDim.x + threadIdx.x) * 4;
    if (e + 3 < E) {
        int4 s4 = *(const int4*)(ei + e);
        int4 d4 = *(const int4*)(ei + E + e);
        atomicAdd(&degS[s4.x], 1.0f); atomicAdd(&degS[s4.y], 1.0f);
        atomicAdd(&degS[s4.z], 1.0f); atomicAdd(&degS[s4.w], 1.0f);
        atomicAdd(&cnt[d4.x], 1); atomicAdd(&cnt[d4.y], 1);
        atomicAdd(&cnt[d4.z], 1); atomicAdd(&cnt[d4.w], 1);
    } else {
        for (int q = e; q < E; ++q) {
            atomicAdd(&degS[ei[q]], 1.0f);
            atomicAdd(&cnt[ei[E + q]], 1);
        }
    }
}

__global__ void dinv_kernel(const float* __restrict__ degS, float* __restrict__ dinv, int N) {
    int n = blockIdx.x * blockDim.x + threadIdx.x;
    if (n < N) {
        float dg = degS[n];
        dinv[n] = dg > 0.0f ? rsqrtf(fmaxf(dg, 1.0f)) : 0.0f;
    }
}

// ---------------- 3-kernel exclusive scan of cnt -> row (+cur copy) ----------
__global__ void scanA_kernel(const int* __restrict__ cnt, int* __restrict__ bs, int N) {
    __shared__ int s[256];
    int t = threadIdx.x, n = blockIdx.x * 256 + t;
    s[t] = (n < N) ? cnt[n] : 0;
    __syncthreads();
    for (int off = 128; off > 0; off >>= 1) {
        if (t < off) s[t] += s[t + off];
        __syncthreads();
    }
    if (t == 0) bs[blockIdx.x] = s[0];
}

__global__ void scanB_kernel(int* __restrict__ bs, int nb) {
    __shared__ int s[1024];
    int t = threadIdx.x;
    int orig = (t < nb) ? bs[t] : 0;
    s[t] = orig;
    __syncthreads();
    for (int off = 1; off < 1024; off <<= 1) {
        int v = (t >= off) ? s[t - off] : 0;
        __syncthreads();
        s[t] += v;
        __syncthreads();
    }
    if (t < nb) bs[t] = s[t] - orig;   // exclusive
}

__global__ void scanC_kernel(const int* __restrict__ cnt, const int* __restrict__ bs,
                             int* __restrict__ row, int* __restrict__ cur, int N) {
    __shared__ int s[256];
    int t = threadIdx.x, n = blockIdx.x * 256 + t;
    int c = (n < N) ? cnt[n] : 0;
    s[t] = c;
    __syncthreads();
    for (int off = 1; off < 256; off <<= 1) {
        int v = (t >= off) ? s[t - off] : 0;
        __syncthreads();
        s[t] += v;
        __syncthreads();
    }
    if (n < N) {
        int r = bs[blockIdx.x] + s[t] - c;
        row[n] = r;
        cur[n] = r;
    }
}

// ---------------- fill CSR: (src, dinv[src]) sorted by dst ------------------
__global__ void fill_kernel(const int* __restrict__ ei, int E,
                            const float* __restrict__ dinv,
                            int* __restrict__ cur, int2* __restrict__ srcw) {
    int e = blockIdx.x * blockDim.x + threadIdx.x;
    if (e < E) {
        int s = ei[e], d = ei[E + e];
        int p = atomicAdd(&cur[d], 1);
        srcw[p] = make_int2(s, __float_as_int(dinv[s]));
    }
}

// ---------------- W2eff: rows 0..63 = W2[0]-W2[2]; 64..127 = W2[1]; 128..191 = 2*W2[2]
__global__ void w2eff_kernel(const float* __restrict__ W2, float* __restrict__ W2e) {
    int idx = blockIdx.x * blockDim.x + threadIdx.x;
    if (idx < 192 * 64) {
        int r = idx >> 6;
        float v;
        if (r < 64)       v = W2[idx] - W2[8192 + idx];
        else if (r < 128) v = W2[idx];
        else              v = 2.0f * W2[idx];
        W2e[idx] = v;
    }
}

// ---------------- pack h (fp32) -> chunked bf16x2 table ----------------------
__global__ void packh_kernel(const float* __restrict__ h, unsigned int* __restrict__ hbf,
                             int N) {
    int i = blockIdx.x * blockDim.x + threadIdx.x;   // over 32N u32 words
    if (i < 32 * N) {
        int n = i >> 5, p = i & 31;
        float2 v = ((const float2*)h)[i];
        hbf[(size_t)(p >> 3) * ((size_t)N * 8) + (size_t)n * 8 + (p & 7)] = pack2(v.x, v.y);
    }
}

// ---------------- 2-channel gather propagation (input path) -----------------
__global__ void gather2_kernel(const int* __restrict__ row, const int* __restrict__ cnt,
                               const int2* __restrict__ srcw, const float* __restrict__ dinv,
                               const float* __restrict__ xsrc, float* __restrict__ dst, int N) {
    int n = blockIdx.x * blockDim.x + threadIdx.x;
    if (n >= N) return;
    int start = row[n], k = cnt[n];
    float a0 = 0.0f, a1 = 0.0f;
    const float2* x2 = (const float2*)xsrc;
    for (int q = 0; q < k; ++q) {
        int2 rec = srcw[start + q];
        float w = __int_as_float(rec.y);
        float2 xv = x2[rec.x];
        a0 = fmaf(w, xv.x, a0);
        a1 = fmaf(w, xv.y, a1);
    }
    float dn = dinv[n];
    dst[2 * n]     = -dn * a0;
    dst[2 * n + 1] = -dn * a1;
}

// ---------------- chunked 16-channel gather propagation ----------------------
// Sub-table per chunk = N*32B = 3.2MB -> L2-resident. Chunk is the slow grid
// dim so blocks of one chunk run ~together. Wave per (node, chunk):
// 16 edge slots x 4 lanes x uint2; k<=16 done in one shot.
__global__ void gather64c_kernel(const int* __restrict__ row, const int* __restrict__ cnt,
                                 const int2* __restrict__ srcw, const float* __restrict__ dinv,
                                 const unsigned int* __restrict__ src,
                                 unsigned int* __restrict__ dst, int N, int nodeblocks) {
    int c  = blockIdx.x / nodeblocks;            // chunk 0..3
    int nb = blockIdx.x - c * nodeblocks;
    int wu = __builtin_amdgcn_readfirstlane((int)threadIdx.x >> 6);
    int n  = nb * 4 + wu;
    if (n >= N) return;
    int lane = threadIdx.x & 63;
    int t    = lane & 3;       // u32-pair within chunk row (channels 4t..4t+3)
    int slot = lane >> 2;      // edge slot 0..15
    int start = row[n], k = cnt[n];
    const unsigned int* stab = src + (size_t)c * ((size_t)N * 8);
    float a0 = 0, a1 = 0, a2 = 0, a3 = 0;
    for (int e = slot; e < k; e += 16) {
        int2 rec = srcw[start + e];
        float w = __int_as_float(rec.y);
        const uint2* r2 = (const uint2*)(stab + (size_t)rec.x * 8);
        uint2 v = r2[t];
        a0 = fmaf(w, lo2f(v.x), a0); a1 = fmaf(w, hi2f(v.x), a1);
        a2 = fmaf(w, lo2f(v.y), a2); a3 = fmaf(w, hi2f(v.y), a3);
    }
    a0 += __shfl_xor(a0, 4);  a1 += __shfl_xor(a1, 4);
    a2 += __shfl_xor(a2, 4);  a3 += __shfl_xor(a3, 4);
    a0 += __shfl_xor(a0, 8);  a1 += __shfl_xor(a1, 8);
    a2 += __shfl_xor(a2, 8);  a3 += __shfl_xor(a3, 8);
    a0 += __shfl_xor(a0, 16); a1 += __shfl_xor(a1, 16);
    a2 += __shfl_xor(a2, 16); a3 += __shfl_xor(a3, 16);
    a0 += __shfl_xor(a0, 32); a1 += __shfl_xor(a1, 32);
    a2 += __shfl_xor(a2, 32); a3 += __shfl_xor(a3, 32);
    if (slot == 0) {
        float dn = -dinv[n];
        uint2 o;
        o.x = pack2(dn * a0, dn * a1);
        o.y = pack2(dn * a2, dn * a3);
        ((uint2*)(dst + (size_t)c * ((size_t)N * 8) + (size_t)n * 8))[t] = o;
    }
}

// ---------------- fused input_conv + hidden_conv + GRU gates ----------------
// Block = 64 nodes, 256 threads (4 waves). 3 LDS buffers (24KB) -> 6 blocks/CU:
//  s_A: h      (staging->ph1), then ic   (restage->ph3)
//  s_B: t1     (staging->ph1), then r*hc (ph2->ph3)
//  s_C: pp     (staging->ph1), then hc   (ph1->ph2)
// Wave w computes channels [16w,16w+16) for all 64 nodes (lane = node).
__global__ __launch_bounds__(256, 6) void gate_fused_kernel(
    float* __restrict__ out,
    const float* __restrict__ x,
    const float* __restrict__ h,
    const float* __restrict__ txa,
    const float* __restrict__ txb,
    const unsigned int* __restrict__ t1u,   // chunked bf16 prop(h)
    const unsigned int* __restrict__ ppu,   // chunked bf16 prop(prop(h))
    const float* __restrict__ W1, const float* __restrict__ b1,
    const float* __restrict__ W2e, const float* __restrict__ b2,
    const float* __restrict__ Wz, const float* __restrict__ bz,
    const float* __restrict__ Wr, const float* __restrict__ br,
    const float* __restrict__ Wc, const float* __restrict__ bc,
    int N) {
    __shared__ unsigned int s_A[2048];
    __shared__ unsigned int s_B[2048];
    __shared__ unsigned int s_C[2048];

    int tid = threadIdx.x;
    int l   = tid & 63;                                 // node in compute phases
    int wu  = __builtin_amdgcn_readfirstlane(tid >> 6); // wave id
    int wbase = wu * 16;
    int b0 = blockIdx.x * 64;

    int pc  = tid & 31;          // channel pair 0..31
    int sub = (tid >> 5) & 1;    // which of the wave's 2 nodes per rep

    const float2* h2  = (const float2*)h;
    const float2* x2  = (const float2*)x;
    const float2* ta2 = (const float2*)txa;
    const float2* tb2 = (const float2*)txb;

    float2 b1v  = ((const float2*)b1)[pc];
    float2 w1r0 = ((const float2*)(W1      ))[pc];
    float2 w1r1 = ((const float2*)(W1 +  64))[pc];
    float2 w1r2 = ((const float2*)(W1 + 128))[pc];
    float2 w1r3 = ((const float2*)(W1 + 192))[pc];
    float2 w1r4 = ((const float2*)(W1 + 256))[pc];
    float2 w1r5 = ((const float2*)(W1 + 320))[pc];

    // ---- staging: h, t1, pp ----
    #pragma unroll
    for (int rep = 0; rep < 8; ++rep) {
        int n = rep * 8 + wu * 2 + sub;
        int g = b0 + n;
        int gc = g < N ? g : N - 1;
        float2 hv = h2[(size_t)gc * 32 + pc];
        int si = (n << 5) | ((pc + n) & 31);
        s_A[si] = pack2(hv.x, hv.y);
        s_B[si] = chread(t1u, N, gc, pc);
        s_C[si] = chread(ppu, N, gc, pc);
    }
    __syncthreads();

    int rbase = l << 5;

    // ---- phase 1: hidden conv, K=192 over [h; t1; pp] with W2eff ----
    float acc[16];
    #pragma unroll
    for (int j = 0; j < 16; ++j) acc[j] = b2[wbase + j];
    #pragma unroll 4
    for (int p = 0; p < 32; ++p) {
        unsigned int u = s_A[rbase | ((p + l) & 31)];
        float f0 = lo2f(u), f1 = hi2f(u);
        const float* wr0 = W2e + (2 * p) * 64 + wbase;
        #pragma unroll
        for (int j = 0; j < 16; ++j)
            acc[j] = fmaf(f0, wr0[j], fmaf(f1, wr0[64 + j], acc[j]));
    }
    #pragma unroll 4
    for (int p = 0; p < 32; ++p) {
        unsigned int u = s_B[rbase | ((p + l) & 31)];
        float f0 = lo2f(u), f1 = hi2f(u);
        const float* wr0 = W2e + (64 + 2 * p) * 64 + wbase;
        #pragma unroll
        for (int j = 0; j < 16; ++j)
            acc[j] = fmaf(f0, wr0[j], fmaf(f1, wr0[64 + j], acc[j]));
    }
    #pragma unroll 4
    for (int p = 0; p < 32; ++p) {
        unsigned int u = s_C[rbase | ((p + l) & 31)];
        float f0 = lo2f(u), f1 = hi2f(u);
        const float* wr0 = W2e + (128 + 2 * p) * 64 + wbase;
        #pragma unroll
        for (int j = 0; j < 16; ++j)
            acc[j] = fmaf(f0, wr0[j], fmaf(f1, wr0[64 + j], acc[j]));
    }
    __syncthreads();   // all phase-1 reads done before buffer reuse

    // ---- restage: ic -> s_A, hc -> s_C ----
    #pragma unroll
    for (int rep = 0; rep < 8; ++rep) {
        int n = rep * 8 + wu * 2 + sub;
        int g = b0 + n;
        int gc = g < N ? g : N - 1;
        float2 xv  = x2[gc];
        float2 tav = ta2[gc];
        float2 tbv = tb2[gc];
        float t20 = 2.0f * tbv.x - xv.x, t21 = 2.0f * tbv.y - xv.y;
        float ic0 = b1v.x + xv.x * w1r0.x + xv.y * w1r1.x + tav.x * w1r2.x
                  + tav.y * w1r3.x + t20 * w1r4.x + t21 * w1r5.x;
        float ic1 = b1v.y + xv.x * w1r0.y + xv.y * w1r1.y + tav.x * w1r2.y
                  + tav.y * w1r3.y + t20 * w1r4.y + t21 * w1r5.y;
        int si = (n << 5) | ((pc + n) & 31);
        s_A[si] = pack2(ic0, ic1);
    }
    #pragma unroll
    for (int j = 0; j < 8; ++j)
        s_C[rbase | (((wbase >> 1) + j + l) & 31)] = pack2(acc[2 * j], acc[2 * j + 1]);
    __syncthreads();

    // ---- phase 2: z and r gates over [ic; hc] (hc rows at 64+ch) ----
    float az[16], ar[16];
    #pragma unroll
    for (int j = 0; j < 16; ++j) { az[j] = bz[wbase + j]; ar[j] = br[wbase + j]; }
    #pragma unroll 2
    for (int p = 0; p < 32; ++p) {
        unsigned int u = s_A[rbase | ((p + l) & 31)];
        float f0 = lo2f(u), f1 = hi2f(u);
        const float* wz0 = Wz + (2 * p) * 64 + wbase;
        const float* wr0 = Wr + (2 * p) * 64 + wbase;
        #pragma unroll
        for (int j = 0; j < 16; ++j) {
            az[j] = fmaf(f0, wz0[j], fmaf(f1, wz0[64 + j], az[j]));
            ar[j] = fmaf(f0, wr0[j], fmaf(f1, wr0[64 + j], ar[j]));
        }
    }
    #pragma unroll 2
    for (int p = 0; p < 32; ++p) {
        unsigned int u = s_C[rbase | ((p + l) & 31)];
        float f0 = lo2f(u), f1 = hi2f(u);
        const float* wz0 = Wz + (64 + 2 * p) * 64 + wbase;
        const float* wr0 = Wr + (64 + 2 * p) * 64 + wbase;
        #pragma unroll
        for (int j = 0; j < 16; ++j) {
            az[j] = fmaf(f0, wz0[j], fmaf(f1, wz0[64 + j], az[j]));
            ar[j] = fmaf(f0, wr0[j], fmaf(f1, wr0[64 + j], ar[j]));
        }
    }
    float zz[16];
    #pragma unroll
    for (int j = 0; j < 16; ++j)
        zz[j] = 1.0f / (1.0f + __expf(-az[j]));
    #pragma unroll
    for (int j = 0; j < 8; ++j) {
        float r0 = 1.0f / (1.0f + __expf(-ar[2 * j]));
        float r1 = 1.0f / (1.0f + __expf(-ar[2 * j + 1]));
        s_B[rbase | (((wbase >> 1) + j + l) & 31)] =
            pack2(r0 * acc[2 * j], r1 * acc[2 * j + 1]);
    }
    __syncthreads();

    // ---- phase 3: candidate over [ic; r*hc] ----
    float ac[16];
    #pragma unroll
    for (int j = 0; j < 16; ++j) ac[j] = bc[wbase + j];
    #pragma unroll 4
    for (int p = 0; p < 32; ++p) {
        unsigned int u = s_A[rbase | ((p + l) & 31)];
        float f0 = lo2f(u), f1 = hi2f(u);
        const float* wc0 = Wc + (2 * p) * 64 + wbase;
        #pragma unroll
        for (int j = 0; j < 16; ++j)
            ac[j] = fmaf(f0, wc0[j], fmaf(f1, wc0[64 + j], ac[j]));
    }
    #pragma unroll 4
    for (int p = 0; p < 32; ++p) {
        unsigned int u = s_B[rbase | ((p + l) & 31)];
        float f0 = lo2f(u), f1 = hi2f(u);
        const float* wc0 = Wc + (64 + 2 * p) * 64 + wbase;
        #pragma unroll
        for (int j = 0; j < 16; ++j)
            ac[j] = fmaf(f0, wc0[j], fmaf(f1, wc0[64 + j], ac[j]));
    }

    int gl = b0 + l;
    if (gl < N) {
        const float2* hrow = (const float2*)(h + (size_t)gl * 64 + wbase);
        float2* orow = (float2*)(out + (size_t)gl * 64 + wbase);
        #pragma unroll
        for (int j = 0; j < 8; ++j) {
            float2 hv = hrow[j];
            float a0 = fminf(fmaxf(ac[2 * j],     -40.0f), 40.0f);
            float a1 = fminf(fmaxf(ac[2 * j + 1], -40.0f), 40.0f);
            float e0 = __expf(2.0f * a0);
            float e1 = __expf(2.0f * a1);
            float ht0 = 1.0f - 2.0f / (e0 + 1.0f);
            float ht1 = 1.0f - 2.0f / (e1 + 1.0f);
            float o0 = zz[2 * j]     * hv.x + (1.0f - zz[2 * j])     * ht0;
            float o1 = zz[2 * j + 1] * hv.y + (1.0f - zz[2 * j + 1]) * ht1;
            orow[j] = make_float2(o0, o1);
        }
    }
}

extern "C" void kernel_launch(void* const* d_in, const int* in_sizes, int n_in,
                              void* d_out, int out_size, void* d_ws, size_t ws_size,
                              hipStream_t stream) {
    const float* x  = (const float*)d_in[0];
    const int*   ei = (const int*)  d_in[1];
    const float* h  = (const float*)d_in[2];
    const float* W1 = (const float*)d_in[3];
    const float* b1 = (const float*)d_in[4];
    const float* W2 = (const float*)d_in[5];
    const float* b2 = (const float*)d_in[6];
    const float* Wz = (const float*)d_in[7];
    const float* bz = (const float*)d_in[8];
    const float* Wr = (const float*)d_in[9];
    const float* br = (const float*)d_in[10];
    const float* Wc = (const float*)d_in[11];
    const float* bc = (const float*)d_in[12];
    float* out = (float*)d_out;

    int N = in_sizes[0] / 2;     // 100000
    int E = in_sizes[1] / 2;     // 1600000
    int NB = (N + 255) / 256;    // scan blocks (391)

    // workspace layout (4B units):
    char* wsb = (char*)d_ws;
    float* degS = (float*)wsb;                              // N  (memset)
    int*   cnt  = (int*)  (wsb + (size_t)N * 4);            // N  (memset)
    float* dinv = (float*)(wsb + (size_t)2 * N * 4);        // N
    int*   row  = (int*)  (wsb + (size_t)3 * N * 4);        // N
    int*   cur  = (int*)  (wsb + (size_t)4 * N * 4);        // N
    float* txa  = (float*)(wsb + (size_t)5 * N * 4);        // 2N
    float* txb  = (float*)(wsb + (size_t)7 * N * 4);        // 2N
    int*   bs   = (int*)  (wsb + (size_t)9 * N * 4);        // 1024
    float* W2e  = (float*)(wsb + ((size_t)9 * N + 1024) * 4);          // 12288
    int2*  srcw = (int2*) (wsb + ((size_t)9 * N + 13312) * 4);         // 2E u32
    unsigned int* bufA = (unsigned int*)(wsb + ((size_t)9 * N + 13312 + 2 * (size_t)E) * 4);  // 32N (chunked)
    unsigned int* hpp  = (unsigned int*)(wsb + ((size_t)41 * N + 13312 + 2 * (size_t)E) * 4); // 32N (chunked)

    // zero only the histogram accumulators
    hipMemsetAsync(wsb, 0, (size_t)2 * N * 4, stream);

    hist_kernel <<<(E / 4 + 255) / 256, 256, 0, stream>>>(ei, E, degS, cnt);
    dinv_kernel <<<NB, 256, 0, stream>>>(degS, dinv, N);

    // CSR build (srcs sorted by dst, weight = dinv[src] fused in)
    scanA_kernel<<<NB, 256, 0, stream>>>(cnt, bs, N);
    scanB_kernel<<<1, 1024, 0, stream>>>(bs, NB);
    scanC_kernel<<<NB, 256, 0, stream>>>(cnt, bs, row, cur, N);
    fill_kernel <<<(E + 255) / 256, 256, 0, stream>>>(ei, E, dinv, cur, srcw);

    w2eff_kernel<<<(192 * 64 + 255) / 256, 256, 0, stream>>>(W2, W2e);
    packh_kernel<<<(32 * N + 255) / 256, 256, 0, stream>>>(h, hpp, N);

    // input path: x -> txa -> txb (2 channels, gather)
    gather2_kernel<<<NB, 256, 0, stream>>>(row, cnt, srcw, dinv, x,   txa, N);
    gather2_kernel<<<NB, 256, 0, stream>>>(row, cnt, srcw, dinv, txa, txb, N);

    // hidden path: hbf -> bufA -> ppbf (chunked bf16; chunk = slow grid dim)
    int nodeblocks = (N + 3) / 4;
    gather64c_kernel<<<4 * nodeblocks, 256, 0, stream>>>(row, cnt, srcw, dinv, hpp,  bufA, N, nodeblocks);
    gather64c_kernel<<<4 * nodeblocks, 256, 0, stream>>>(row, cnt, srcw, dinv, bufA, hpp,  N, nodeblocks);

    // fused input_conv + hidden_conv + gates (24KB LDS -> 6 blocks/CU)
    int T = (N + 63) / 64;
    gate_fused_kernel<<<T, 256, 0, stream>>>(
        out, x, h, txa, txb, bufA, hpp, W1, b1, W2e, b2, Wz, bz, Wr, br, Wc, bc, N);
}

// Round 7
// 458.512 us; speedup vs baseline: 1.4918x; 1.4918x over previous
//
#include <hip/hip_runtime.h>
#include <hip/hip_bf16.h>
#include <math.h>

#define HID 64

typedef __attribute__((ext_vector_type(8))) short bf16x8;
typedef __attribute__((ext_vector_type(4))) float f32x4;

// ---- bf16 pack/unpack (RNE) ----
__device__ __forceinline__ unsigned int bf16r(float f) {
    unsigned int u = __float_as_uint(f);
    return (u + 0x7fffu + ((u >> 16) & 1u)) >> 16;
}
__device__ __forceinline__ unsigned int pack2(float a, float b) {
    return bf16r(a) | (bf16r(b) << 16);
}
__device__ __forceinline__ float lo2f(unsigned int u) { return __uint_as_float(u << 16); }
__device__ __forceinline__ float hi2f(unsigned int u) { return __uint_as_float(u & 0xffff0000u); }

__device__ __forceinline__ bf16x8 asbf(uint4 u) {
    union { uint4 u4; bf16x8 b; } c; c.u4 = u; return c.b;
}
__device__ __forceinline__ void load8(const float* p, float* d) {
    float4 a = *(const float4*)p, b = *(const float4*)(p + 4);
    d[0]=a.x; d[1]=a.y; d[2]=a.z; d[3]=a.w; d[4]=b.x; d[5]=b.y; d[6]=b.z; d[7]=b.w;
}

// ---------------- histogram (scalar, round-5 proven) ----------------
__global__ void hist_kernel(const int* __restrict__ ei, int E,
                            float* __restrict__ degS, int* __restrict__ cnt) {
    int e = blockIdx.x * blockDim.x + threadIdx.x;
    if (e < E) {
        atomicAdd(&degS[ei[e]], 1.0f);
        atomicAdd(&cnt[ei[E + e]], 1);
    }
}

__global__ void dinv_kernel(const float* __restrict__ degS, float* __restrict__ dinv, int N) {
    int n = blockIdx.x * blockDim.x + threadIdx.x;
    if (n < N) {
        float dg = degS[n];
        dinv[n] = dg > 0.0f ? rsqrtf(fmaxf(dg, 1.0f)) : 0.0f;
    }
}

// ---------------- 3-kernel exclusive scan of cnt -> row (+cur copy) ----------
__global__ void scanA_kernel(const int* __restrict__ cnt, int* __restrict__ bs, int N) {
    __shared__ int s[256];
    int t = threadIdx.x, n = blockIdx.x * 256 + t;
    s[t] = (n < N) ? cnt[n] : 0;
    __syncthreads();
    for (int off = 128; off > 0; off >>= 1) {
        if (t < off) s[t] += s[t + off];
        __syncthreads();
    }
    if (t == 0) bs[blockIdx.x] = s[0];
}

__global__ void scanB_kernel(int* __restrict__ bs, int nb) {
    __shared__ int s[1024];
    int t = threadIdx.x;
    int orig = (t < nb) ? bs[t] : 0;
    s[t] = orig;
    __syncthreads();
    for (int off = 1; off < 1024; off <<= 1) {
        int v = (t >= off) ? s[t - off] : 0;
        __syncthreads();
        s[t] += v;
        __syncthreads();
    }
    if (t < nb) bs[t] = s[t] - orig;   // exclusive
}

__global__ void scanC_kernel(const int* __restrict__ cnt, const int* __restrict__ bs,
                             int* __restrict__ row, int* __restrict__ cur, int N) {
    __shared__ int s[256];
    int t = threadIdx.x, n = blockIdx.x * 256 + t;
    int c = (n < N) ? cnt[n] : 0;
    s[t] = c;
    __syncthreads();
    for (int off = 1; off < 256; off <<= 1) {
        int v = (t >= off) ? s[t - off] : 0;
        __syncthreads();
        s[t] += v;
        __syncthreads();
    }
    if (n < N) {
        int r = bs[blockIdx.x] + s[t] - c;
        row[n] = r;
        cur[n] = r;
    }
}

// ---------------- fill CSR: (src, dinv[src]) sorted by dst ------------------
__global__ void fill_kernel(const int* __restrict__ ei, int E,
                            const float* __restrict__ dinv,
                            int* __restrict__ cur, int2* __restrict__ srcw) {
    int e = blockIdx.x * blockDim.x + threadIdx.x;
    if (e < E) {
        int s = ei[e], d = ei[E + e];
        int p = atomicAdd(&cur[d], 1);
        srcw[p] = make_int2(s, __float_as_int(dinv[s]));
    }
}

// ---------------- pack transposed bf16 weight tables -------------------------
// WT layout (u32 units):
//   [0,6144):      W2eT[col 0..63][kpair 0..95]   (K=192, eff rows)
//   [6144,14336):  WzrT[col 0..127][kpair 0..63]  (cols 0..63=Wz, 64..127=Wr)
//   [14336,18432): WcT [col 0..63][kpair 0..63]
__global__ void packwT_kernel(const float* __restrict__ W2, const float* __restrict__ Wz,
                              const float* __restrict__ Wr, const float* __restrict__ Wc,
                              unsigned int* __restrict__ WT) {
    int idx = blockIdx.x * blockDim.x + threadIdx.x;
    if (idx >= 18432) return;
    float v0, v1;
    if (idx < 6144) {
        int c = idx / 96, kk = idx % 96;
        int k0 = 2 * kk;
        float a0, a1;
        if (k0 < 64) {
            a0 = W2[k0 * 64 + c] - W2[8192 + k0 * 64 + c];
            a1 = W2[(k0 + 1) * 64 + c] - W2[8192 + (k0 + 1) * 64 + c];
        } else if (k0 < 128) {
            a0 = W2[4096 + (k0 - 64) * 64 + c];
            a1 = W2[4096 + (k0 - 63) * 64 + c];
        } else {
            a0 = 2.0f * W2[8192 + (k0 - 128) * 64 + c];
            a1 = 2.0f * W2[8192 + (k0 - 127) * 64 + c];
        }
        v0 = a0; v1 = a1;
    } else if (idx < 14336) {
        int t = idx - 6144;
        int c = t / 64, kk = t % 64, k0 = 2 * kk;
        const float* Ws = (c < 64) ? Wz : Wr;
        int cc = c & 63;
        v0 = Ws[k0 * 64 + cc];
        v1 = Ws[(k0 + 1) * 64 + cc];
    } else {
        int t = idx - 14336;
        int c = t / 64, kk = t % 64, k0 = 2 * kk;
        v0 = Wc[k0 * 64 + c];
        v1 = Wc[(k0 + 1) * 64 + c];
    }
    WT[idx] = pack2(v0, v1);
}

// ---------------- pack h (fp32) -> monolithic bf16x2 table -------------------
__global__ void packh_kernel(const float* __restrict__ h, unsigned int* __restrict__ hbf,
                             int total2) {
    int i = blockIdx.x * blockDim.x + threadIdx.x;
    if (i < total2) {
        float2 v = ((const float2*)h)[i];
        hbf[i] = pack2(v.x, v.y);
    }
}

// ---------------- 2-channel gather propagation (input path) -----------------
__global__ void gather2_kernel(const int* __restrict__ row, const int* __restrict__ cnt,
                               const int2* __restrict__ srcw, const float* __restrict__ dinv,
                               const float* __restrict__ xsrc, float* __restrict__ dst, int N) {
    int n = blockIdx.x * blockDim.x + threadIdx.x;
    if (n >= N) return;
    int start = row[n], k = cnt[n];
    float a0 = 0.0f, a1 = 0.0f;
    const float2* x2 = (const float2*)xsrc;
    for (int q = 0; q < k; ++q) {
        int2 rec = srcw[start + q];
        float w = __int_as_float(rec.y);
        float2 xv = x2[rec.x];
        a0 = fmaf(w, xv.x, a0);
        a1 = fmaf(w, xv.y, a1);
    }
    float dn = dinv[n];
    dst[2 * n]     = -dn * a0;
    dst[2 * n + 1] = -dn * a1;
}

// ---------------- 64-channel gather propagation, bf16 rows (round-5) ---------
__global__ void gather64_kernel(const int* __restrict__ row, const int* __restrict__ cnt,
                                const int2* __restrict__ srcw, const float* __restrict__ dinv,
                                const unsigned int* __restrict__ src,  // bf16 rows, 32 u32/row
                                unsigned int* __restrict__ dst, int N) {
    int wu = __builtin_amdgcn_readfirstlane((int)threadIdx.x >> 6);
    int n = blockIdx.x * 4 + wu;
    if (n >= N) return;
    int lane = threadIdx.x & 63;
    int t    = lane & 7;      // u32 quad within row (channels 8t..8t+7)
    int slot = lane >> 3;     // edge slot 0..7
    int start = row[n], k = cnt[n];
    float a0 = 0, a1 = 0, a2 = 0, a3 = 0, a4 = 0, a5 = 0, a6 = 0, a7 = 0;
    for (int e = slot; e < k; e += 8) {
        int2 rec = srcw[start + e];
        float w = __int_as_float(rec.y);
        const uint4* r4 = (const uint4*)(src + (size_t)rec.x * 32);
        uint4 v = r4[t];
        a0 = fmaf(w, lo2f(v.x), a0); a1 = fmaf(w, hi2f(v.x), a1);
        a2 = fmaf(w, lo2f(v.y), a2); a3 = fmaf(w, hi2f(v.y), a3);
        a4 = fmaf(w, lo2f(v.z), a4); a5 = fmaf(w, hi2f(v.z), a5);
        a6 = fmaf(w, lo2f(v.w), a6); a7 = fmaf(w, hi2f(v.w), a7);
    }
    a0 += __shfl_xor(a0, 8);  a1 += __shfl_xor(a1, 8);
    a2 += __shfl_xor(a2, 8);  a3 += __shfl_xor(a3, 8);
    a4 += __shfl_xor(a4, 8);  a5 += __shfl_xor(a5, 8);
    a6 += __shfl_xor(a6, 8);  a7 += __shfl_xor(a7, 8);
    a0 += __shfl_xor(a0, 16); a1 += __shfl_xor(a1, 16);
    a2 += __shfl_xor(a2, 16); a3 += __shfl_xor(a3, 16);
    a4 += __shfl_xor(a4, 16); a5 += __shfl_xor(a5, 16);
    a6 += __shfl_xor(a6, 16); a7 += __shfl_xor(a7, 16);
    a0 += __shfl_xor(a0, 32); a1 += __shfl_xor(a1, 32);
    a2 += __shfl_xor(a2, 32); a3 += __shfl_xor(a3, 32);
    a4 += __shfl_xor(a4, 32); a5 += __shfl_xor(a5, 32);
    a6 += __shfl_xor(a6, 32); a7 += __shfl_xor(a7, 32);
    if (slot == 0) {
        float dn = -dinv[n];
        uint4 o;
        o.x = pack2(dn * a0, dn * a1);
        o.y = pack2(dn * a2, dn * a3);
        o.z = pack2(dn * a4, dn * a5);
        o.w = pack2(dn * a6, dn * a7);
        ((uint4*)(dst + (size_t)n * 32))[t] = o;
    }
}

// ---------------- MFMA fused input_conv + hidden_conv + GRU gates -----------
// Block = 256 threads = 4 independent waves; wave = 32 nodes (2 M-tiles of 16).
// 16x16x32 bf16 MFMA. A-frag: row=lane&15 (node), k=8*(lane>>4)+j.
// B-frag: col=lane&15 (out ch), same k -> transposed packed weight tables.
// C/D: col=lane&15 (ch), row=(lane>>4)*4+reg (node)  [m89-verified].
// GEMM1: hc = [h|t1|pp](K=192) @ W2eff.  GEMM2: [z|r] = [ic|hc](K=128) @ [Wz|Wr].
// GEMM3: cand = [ic|r*hc](K=128) @ Wc.  Per-wave LDS transposes for hc, r*hc.
__global__ __launch_bounds__(256) void gate_mfma_kernel(
    float* __restrict__ out,
    const float* __restrict__ x,
    const float* __restrict__ h,
    const float* __restrict__ txa,
    const float* __restrict__ txb,
    const unsigned int* __restrict__ t1u,   // bf16 rows: prop(h)
    const unsigned int* __restrict__ ppu,   // bf16 rows: prop(prop(h))
    const float* __restrict__ W1, const float* __restrict__ b1,
    const unsigned int* __restrict__ WT,
    const float* __restrict__ b2, const float* __restrict__ bz,
    const float* __restrict__ br, const float* __restrict__ bc,
    int N) {
    __shared__ unsigned short lds16[4][32][72];   // per-wave 32x64 transpose pad->72

    int tid  = threadIdx.x;
    int lane = tid & 63;
    int wu   = __builtin_amdgcn_readfirstlane(tid >> 6);
    int q    = lane >> 4;      // 0..3
    int r16  = lane & 15;
    int base = blockIdx.x * 128 + wu * 32;

    int nA[2];
    nA[0] = min(base + r16, N - 1);
    nA[1] = min(base + 16 + r16, N - 1);

    const unsigned int* W2eT = WT;
    const unsigned int* WzrT = WT + 6144;
    const unsigned int* WcT  = WT + 14336;

    // ---- ic A-fragments (computed in frag layout on VALU) ----
    uint4 icA[2][2];
    {
        float2 xv[2], tav[2], tbv[2];
        #pragma unroll
        for (int mt = 0; mt < 2; ++mt) {
            xv[mt]  = ((const float2*)x)[nA[mt]];
            tav[mt] = ((const float2*)txa)[nA[mt]];
            tbv[mt] = ((const float2*)txb)[nA[mt]];
        }
        #pragma unroll
        for (int kf = 0; kf < 2; ++kf) {
            int ch0 = kf * 32 + 8 * q;
            float b1s[8], w0[8], w1s[8], w2[8], w3[8], w4[8], w5[8];
            load8(b1 + ch0, b1s);
            load8(W1 + ch0, w0);       load8(W1 + 64 + ch0, w1s);
            load8(W1 + 128 + ch0, w2); load8(W1 + 192 + ch0, w3);
            load8(W1 + 256 + ch0, w4); load8(W1 + 320 + ch0, w5);
            #pragma unroll
            for (int mt = 0; mt < 2; ++mt) {
                float t20 = 2.0f * tbv[mt].x - xv[mt].x;
                float t21 = 2.0f * tbv[mt].y - xv[mt].y;
                unsigned int pr[4];
                #pragma unroll
                for (int p = 0; p < 4; ++p) {
                    float v0 = b1s[2*p]   + xv[mt].x * w0[2*p]   + xv[mt].y * w1s[2*p]
                             + tav[mt].x * w2[2*p]   + tav[mt].y * w3[2*p]
                             + t20 * w4[2*p]   + t21 * w5[2*p];
                    float v1 = b1s[2*p+1] + xv[mt].x * w0[2*p+1] + xv[mt].y * w1s[2*p+1]
                             + tav[mt].x * w2[2*p+1] + tav[mt].y * w3[2*p+1]
                             + t20 * w4[2*p+1] + t21 * w5[2*p+1];
                    pr[p] = pack2(v0, v1);
                }
                icA[mt][kf] = make_uint4(pr[0], pr[1], pr[2], pr[3]);
            }
        }
    }

    // ---- GEMM1: hc = [h|t1|pp] @ W2eff  (K=192, 6 k-steps) ----
    f32x4 acc1[2][4];
    #pragma unroll
    for (int mt = 0; mt < 2; ++mt)
        #pragma unroll
        for (int nt = 0; nt < 4; ++nt)
            acc1[mt][nt] = (f32x4){0.0f, 0.0f, 0.0f, 0.0f};

    #pragma unroll
    for (int ks = 0; ks < 6; ++ks) {
        bf16x8 a[2];
        if (ks < 2) {
            #pragma unroll
            for (int mt = 0; mt < 2; ++mt) {
                float hs[8];
                load8(h + (size_t)nA[mt] * 64 + ks * 32 + 8 * q, hs);
                uint4 u;
                u.x = pack2(hs[0], hs[1]); u.y = pack2(hs[2], hs[3]);
                u.z = pack2(hs[4], hs[5]); u.w = pack2(hs[6], hs[7]);
                a[mt] = asbf(u);
            }
        } else {
            const unsigned int* tab = (ks < 4) ? t1u : ppu;
            int ksl = ks & 1;
            #pragma unroll
            for (int mt = 0; mt < 2; ++mt)
                a[mt] = asbf(*(const uint4*)(tab + (size_t)nA[mt] * 32 + ksl * 16 + q * 4));
        }
        #pragma unroll
        for (int nt = 0; nt < 4; ++nt) {
            bf16x8 b = asbf(*(const uint4*)(W2eT + (nt * 16 + r16) * 96 + ks * 16 + q * 4));
            #pragma unroll
            for (int mt = 0; mt < 2; ++mt)
                acc1[mt][nt] = __builtin_amdgcn_mfma_f32_16x16x32_bf16(a[mt], b, acc1[mt][nt], 0, 0, 0);
        }
    }

    // ---- add b2; transpose hc via per-wave LDS to A-frag layout ----
    float b2v[4];
    #pragma unroll
    for (int nt = 0; nt < 4; ++nt) b2v[nt] = b2[nt * 16 + r16];
    #pragma unroll
    for (int mt = 0; mt < 2; ++mt)
        #pragma unroll
        for (int nt = 0; nt < 4; ++nt)
            #pragma unroll
            for (int reg = 0; reg < 4; ++reg) {
                acc1[mt][nt][reg] += b2v[nt];
                lds16[wu][mt * 16 + 4 * q + reg][nt * 16 + r16] =
                    (unsigned short)bf16r(acc1[mt][nt][reg]);
            }
    __syncthreads();
    bf16x8 hcA[2][2];
    #pragma unroll
    for (int mt = 0; mt < 2; ++mt)
        #pragma unroll
        for (int kf = 0; kf < 2; ++kf)
            hcA[mt][kf] = asbf(*(const uint4*)&lds16[wu][mt * 16 + r16][kf * 32 + 8 * q]);
    __syncthreads();

    // ---- GEMM2: [z|r] = [ic|hc] @ [Wz|Wr]  (K=128, N=128) ----
    f32x4 acc2[2][8];
    #pragma unroll
    for (int mt = 0; mt < 2; ++mt)
        #pragma unroll
        for (int nt = 0; nt < 8; ++nt)
            acc2[mt][nt] = (f32x4){0.0f, 0.0f, 0.0f, 0.0f};

    #pragma unroll
    for (int kf = 0; kf < 4; ++kf) {
        bf16x8 a[2];
        a[0] = (kf < 2) ? asbf(icA[0][kf]) : hcA[0][kf - 2];
        a[1] = (kf < 2) ? asbf(icA[1][kf]) : hcA[1][kf - 2];
        #pragma unroll
        for (int nt = 0; nt < 8; ++nt) {
            bf16x8 b = asbf(*(const uint4*)(WzrT + (nt * 16 + r16) * 64 + kf * 16 + q * 4));
            #pragma unroll
            for (int mt = 0; mt < 2; ++mt)
                acc2[mt][nt] = __builtin_amdgcn_mfma_f32_16x16x32_bf16(a[mt], b, acc2[mt][nt], 0, 0, 0);
        }
    }

    // ---- gates: z = sig(az), r = sig(ar); write r*hc transpose ----
    float bzv[4], brv[4];
    #pragma unroll
    for (int nt = 0; nt < 4; ++nt) { bzv[nt] = bz[nt * 16 + r16]; brv[nt] = br[nt * 16 + r16]; }
    float zz[2][4][4];
    #pragma unroll
    for (int mt = 0; mt < 2; ++mt)
        #pragma unroll
        for (int nt = 0; nt < 4; ++nt)
            #pragma unroll
            for (int reg = 0; reg < 4; ++reg) {
                zz[mt][nt][reg] = 1.0f / (1.0f + __expf(-(acc2[mt][nt][reg] + bzv[nt])));
                float rr = 1.0f / (1.0f + __expf(-(acc2[mt][nt + 4][reg] + brv[nt])));
                float rhc = rr * acc1[mt][nt][reg];
                lds16[wu][mt * 16 + 4 * q + reg][nt * 16 + r16] = (unsigned short)bf16r(rhc);
            }
    __syncthreads();
    bf16x8 rhcA[2][2];
    #pragma unroll
    for (int mt = 0; mt < 2; ++mt)
        #pragma unroll
        for (int kf = 0; kf < 2; ++kf)
            rhcA[mt][kf] = asbf(*(const uint4*)&lds16[wu][mt * 16 + r16][kf * 32 + 8 * q]);

    // ---- GEMM3: cand = [ic|r*hc] @ Wc  (K=128, N=64) ----
    f32x4 acc3[2][4];
    #pragma unroll
    for (int mt = 0; mt < 2; ++mt)
        #pragma unroll
        for (int nt = 0; nt < 4; ++nt)
            acc3[mt][nt] = (f32x4){0.0f, 0.0f, 0.0f, 0.0f};

    #pragma unroll
    for (int kf = 0; kf < 4; ++kf) {
        bf16x8 a[2];
        a[0] = (kf < 2) ? asbf(icA[0][kf]) : rhcA[0][kf - 2];
        a[1] = (kf < 2) ? asbf(icA[1][kf]) : rhcA[1][kf - 2];
        #pragma unroll
        for (int nt = 0; nt < 4; ++nt) {
            bf16x8 b = asbf(*(const uint4*)(WcT + (nt * 16 + r16) * 64 + kf * 16 + q * 4));
            #pragma unroll
            for (int mt = 0; mt < 2; ++mt)
                acc3[mt][nt] = __builtin_amdgcn_mfma_f32_16x16x32_bf16(a[mt], b, acc3[mt][nt], 0, 0, 0);
        }
    }

    // ---- epilogue: out = z*h + (1-z)*tanh(cand + bc) ----
    float bcv[4];
    #pragma unroll
    for (int nt = 0; nt < 4; ++nt) bcv[nt] = bc[nt * 16 + r16];
    #pragma unroll
    for (int mt = 0; mt < 2; ++mt)
        #pragma unroll
        for (int nt = 0; nt < 4; ++nt)
            #pragma unroll
            for (int reg = 0; reg < 4; ++reg) {
                int node = base + mt * 16 + 4 * q + reg;
                if (node < N) {
                    float a = acc3[mt][nt][reg] + bcv[nt];
                    a = fminf(fmaxf(a, -40.0f), 40.0f);
                    float e = __expf(2.0f * a);
                    float ht = 1.0f - 2.0f / (e + 1.0f);
                    float hv = h[(size_t)node * 64 + nt * 16 + r16];
                    float z = zz[mt][nt][reg];
                    out[(size_t)node * 64 + nt * 16 + r16] = z * hv + (1.0f - z) * ht;
                }
            }
}

extern "C" void kernel_launch(void* const* d_in, const int* in_sizes, int n_in,
                              void* d_out, int out_size, void* d_ws, size_t ws_size,
                              hipStream_t stream) {
    const float* x  = (const float*)d_in[0];
    const int*   ei = (const int*)  d_in[1];
    const float* h  = (const float*)d_in[2];
    const float* W1 = (const float*)d_in[3];
    const float* b1 = (const float*)d_in[4];
    const float* W2 = (const float*)d_in[5];
    const float* b2 = (const float*)d_in[6];
    const float* Wz = (const float*)d_in[7];
    const float* bz = (const float*)d_in[8];
    const float* Wr = (const float*)d_in[9];
    const float* br = (const float*)d_in[10];
    const float* Wc = (const float*)d_in[11];
    const float* bc = (const float*)d_in[12];
    float* out = (float*)d_out;

    int N = in_sizes[0] / 2;     // 100000
    int E = in_sizes[1] / 2;     // 1600000
    int NB = (N + 255) / 256;    // scan blocks (391)

    // workspace layout (u32 units):
    char* wsb = (char*)d_ws;
    float* degS = (float*)wsb;                              // N  (memset)
    int*   cnt  = (int*)  (wsb + (size_t)N * 4);            // N  (memset)
    float* dinv = (float*)(wsb + (size_t)2 * N * 4);        // N
    int*   row  = (int*)  (wsb + (size_t)3 * N * 4);        // N
    int*   cur  = (int*)  (wsb + (size_t)4 * N * 4);        // N
    float* txa  = (float*)(wsb + (size_t)5 * N * 4);        // 2N
    float* txb  = (float*)(wsb + (size_t)7 * N * 4);        // 2N
    int*   bs   = (int*)  (wsb + (size_t)9 * N * 4);        // 1024
    unsigned int* WT = (unsigned int*)(wsb + ((size_t)9 * N + 1024) * 4);   // 18432
    int2*  srcw = (int2*)(wsb + ((size_t)9 * N + 19456) * 4);               // 2E
    unsigned int* bufA = (unsigned int*)(wsb + ((size_t)9 * N + 19456 + 2 * (size_t)E) * 4);  // 32N
    unsigned int* hpp  = (unsigned int*)(wsb + ((size_t)41 * N + 19456 + 2 * (size_t)E) * 4); // 32N

    // zero only the histogram accumulators
    hipMemsetAsync(wsb, 0, (size_t)2 * N * 4, stream);

    hist_kernel <<<(E + 255) / 256, 256, 0, stream>>>(ei, E, degS, cnt);
    dinv_kernel <<<NB, 256, 0, stream>>>(degS, dinv, N);

    // CSR build (srcs sorted by dst, weight = dinv[src] fused in)
    scanA_kernel<<<NB, 256, 0, stream>>>(cnt, bs, N);
    scanB_kernel<<<1, 1024, 0, stream>>>(bs, NB);
    scanC_kernel<<<NB, 256, 0, stream>>>(cnt, bs, row, cur, N);
    fill_kernel <<<(E + 255) / 256, 256, 0, stream>>>(ei, E, dinv, cur, srcw);

    packwT_kernel<<<(18432 + 255) / 256, 256, 0, stream>>>(W2, Wz, Wr, Wc, WT);
    packh_kernel <<<(32 * N + 255) / 256, 256, 0, stream>>>(h, hpp, 32 * N);

    // input path: x -> txa -> txb (2 channels, gather)
    gather2_kernel<<<NB, 256, 0, stream>>>(row, cnt, srcw, dinv, x,   txa, N);
    gather2_kernel<<<NB, 256, 0, stream>>>(row, cnt, srcw, dinv, txa, txb, N);

    // hidden path: hbf -> bufA -> ppbf (monolithic bf16 rows; hpp dual-use)
    int gblocks = (N + 3) / 4;
    gather64_kernel<<<gblocks, 256, 0, stream>>>(row, cnt, srcw, dinv, hpp,  bufA, N);
    gather64_kernel<<<gblocks, 256, 0, stream>>>(row, cnt, srcw, dinv, bufA, hpp,  N);

    // fused MFMA gate (wave = 32 nodes, block = 128 nodes)
    int gateblocks = (N + 127) / 128;
    gate_mfma_kernel<<<gateblocks, 256, 0, stream>>>(
        out, x, h, txa, txb, bufA, hpp, W1, b1, WT, b2, bz, br, bc, N);
}

// Round 8
// 405.339 us; speedup vs baseline: 1.6875x; 1.1312x over previous
//
#include <hip/hip_runtime.h>
#include <hip/hip_bf16.h>
#include <math.h>

#define HID 64

typedef __attribute__((ext_vector_type(8))) short bf16x8;
typedef __attribute__((ext_vector_type(4))) float f32x4;

// ---- bf16 pack/unpack (RNE) ----
__device__ __forceinline__ unsigned int bf16r(float f) {
    unsigned int u = __float_as_uint(f);
    return (u + 0x7fffu + ((u >> 16) & 1u)) >> 16;
}
__device__ __forceinline__ unsigned int pack2(float a, float b) {
    return bf16r(a) | (bf16r(b) << 16);
}
__device__ __forceinline__ float lo2f(unsigned int u) { return __uint_as_float(u << 16); }
__device__ __forceinline__ float hi2f(unsigned int u) { return __uint_as_float(u & 0xffff0000u); }

__device__ __forceinline__ bf16x8 asbf(uint4 u) {
    union { uint4 u4; bf16x8 b; } c; c.u4 = u; return c.b;
}
__device__ __forceinline__ void load8(const float* p, float* d) {
    float4 a = *(const float4*)p, b = *(const float4*)(p + 4);
    d[0]=a.x; d[1]=a.y; d[2]=a.z; d[3]=a.w; d[4]=b.x; d[5]=b.y; d[6]=b.z; d[7]=b.w;
}

// ---------------- histogram + per-edge rank (rank = old cnt value) ----------
__global__ void hist_kernel(const int* __restrict__ ei, int E,
                            float* __restrict__ degS, int* __restrict__ cnt,
                            int* __restrict__ rank) {
    int e = blockIdx.x * blockDim.x + threadIdx.x;
    if (e < E) {
        atomicAdd(&degS[ei[e]], 1.0f);
        rank[e] = atomicAdd(&cnt[ei[E + e]], 1);
    }
}

__global__ void dinv_kernel(const float* __restrict__ degS, float* __restrict__ dinv, int N) {
    int n = blockIdx.x * blockDim.x + threadIdx.x;
    if (n < N) {
        float dg = degS[n];
        dinv[n] = dg > 0.0f ? rsqrtf(fmaxf(dg, 1.0f)) : 0.0f;
    }
}

// ---------------- 3-kernel exclusive scan of cnt -> row ----------------------
__global__ void scanA_kernel(const int* __restrict__ cnt, int* __restrict__ bs, int N) {
    __shared__ int s[256];
    int t = threadIdx.x, n = blockIdx.x * 256 + t;
    s[t] = (n < N) ? cnt[n] : 0;
    __syncthreads();
    for (int off = 128; off > 0; off >>= 1) {
        if (t < off) s[t] += s[t + off];
        __syncthreads();
    }
    if (t == 0) bs[blockIdx.x] = s[0];
}

__global__ void scanB_kernel(int* __restrict__ bs, int nb) {
    __shared__ int s[1024];
    int t = threadIdx.x;
    int orig = (t < nb) ? bs[t] : 0;
    s[t] = orig;
    __syncthreads();
    for (int off = 1; off < 1024; off <<= 1) {
        int v = (t >= off) ? s[t - off] : 0;
        __syncthreads();
        s[t] += v;
        __syncthreads();
    }
    if (t < nb) bs[t] = s[t] - orig;   // exclusive
}

__global__ void scanC_kernel(const int* __restrict__ cnt, const int* __restrict__ bs,
                             int* __restrict__ row, int N) {
    __shared__ int s[256];
    int t = threadIdx.x, n = blockIdx.x * 256 + t;
    int c = (n < N) ? cnt[n] : 0;
    s[t] = c;
    __syncthreads();
    for (int off = 1; off < 256; off <<= 1) {
        int v = (t >= off) ? s[t - off] : 0;
        __syncthreads();
        s[t] += v;
        __syncthreads();
    }
    if (n < N) row[n] = bs[blockIdx.x] + s[t] - c;
}

// ---------------- fill CSR (atomic-free): pos = row[dst] + rank[e] ----------
__global__ void fill_kernel(const int* __restrict__ ei, int E,
                            const float* __restrict__ dinv,
                            const int* __restrict__ row, const int* __restrict__ rank,
                            int2* __restrict__ srcw) {
    int e = blockIdx.x * blockDim.x + threadIdx.x;
    if (e < E) {
        int s = ei[e], d = ei[E + e];
        int p = row[d] + rank[e];
        srcw[p] = make_int2(s, __float_as_int(dinv[s]));
    }
}

// ---------------- pack transposed bf16 weight tables -------------------------
// WT layout (u32 units):
//   [0,6144):      W2eT[col 0..63][kpair 0..95]   (K=192, eff rows)
//   [6144,14336):  WzrT[col 0..127][kpair 0..63]  (cols 0..63=Wz, 64..127=Wr)
//   [14336,18432): WcT [col 0..63][kpair 0..63]
__global__ void packwT_kernel(const float* __restrict__ W2, const float* __restrict__ Wz,
                              const float* __restrict__ Wr, const float* __restrict__ Wc,
                              unsigned int* __restrict__ WT) {
    int idx = blockIdx.x * blockDim.x + threadIdx.x;
    if (idx >= 18432) return;
    float v0, v1;
    if (idx < 6144) {
        int c = idx / 96, kk = idx % 96;
        int k0 = 2 * kk;
        float a0, a1;
        if (k0 < 64) {
            a0 = W2[k0 * 64 + c] - W2[8192 + k0 * 64 + c];
            a1 = W2[(k0 + 1) * 64 + c] - W2[8192 + (k0 + 1) * 64 + c];
        } else if (k0 < 128) {
            a0 = W2[4096 + (k0 - 64) * 64 + c];
            a1 = W2[4096 + (k0 - 63) * 64 + c];
        } else {
            a0 = 2.0f * W2[8192 + (k0 - 128) * 64 + c];
            a1 = 2.0f * W2[8192 + (k0 - 127) * 64 + c];
        }
        v0 = a0; v1 = a1;
    } else if (idx < 14336) {
        int t = idx - 6144;
        int c = t / 64, kk = t % 64, k0 = 2 * kk;
        const float* Ws = (c < 64) ? Wz : Wr;
        int cc = c & 63;
        v0 = Ws[k0 * 64 + cc];
        v1 = Ws[(k0 + 1) * 64 + cc];
    } else {
        int t = idx - 14336;
        int c = t / 64, kk = t % 64, k0 = 2 * kk;
        v0 = Wc[k0 * 64 + c];
        v1 = Wc[(k0 + 1) * 64 + c];
    }
    WT[idx] = pack2(v0, v1);
}

// ---------------- pack h (fp32) -> monolithic bf16x2 table -------------------
__global__ void packh_kernel(const float* __restrict__ h, unsigned int* __restrict__ hbf,
                             int total2) {
    int i = blockIdx.x * blockDim.x + threadIdx.x;
    if (i < total2) {
        float2 v = ((const float2*)h)[i];
        hbf[i] = pack2(v.x, v.y);
    }
}

// ---------------- 2-channel gather propagation (input path) -----------------
__global__ void gather2_kernel(const int* __restrict__ row, const int* __restrict__ cnt,
                               const int2* __restrict__ srcw, const float* __restrict__ dinv,
                               const float* __restrict__ xsrc, float* __restrict__ dst, int N) {
    int n = blockIdx.x * blockDim.x + threadIdx.x;
    if (n >= N) return;
    int start = row[n], k = cnt[n];
    float a0 = 0.0f, a1 = 0.0f;
    const float2* x2 = (const float2*)xsrc;
    for (int q = 0; q < k; ++q) {
        int2 rec = srcw[start + q];
        float w = __int_as_float(rec.y);
        float2 xv = x2[rec.x];
        a0 = fmaf(w, xv.x, a0);
        a1 = fmaf(w, xv.y, a1);
    }
    float dn = dinv[n];
    dst[2 * n]     = -dn * a0;
    dst[2 * n + 1] = -dn * a1;
}

// ---------------- 64-channel gather propagation, bf16 rows -------------------
__global__ void gather64_kernel(const int* __restrict__ row, const int* __restrict__ cnt,
                                const int2* __restrict__ srcw, const float* __restrict__ dinv,
                                const unsigned int* __restrict__ src,  // bf16 rows, 32 u32/row
                                unsigned int* __restrict__ dst, int N) {
    int wu = __builtin_amdgcn_readfirstlane((int)threadIdx.x >> 6);
    int n = blockIdx.x * 4 + wu;
    if (n >= N) return;
    int lane = threadIdx.x & 63;
    int t    = lane & 7;      // u32 quad within row (channels 8t..8t+7)
    int slot = lane >> 3;     // edge slot 0..7
    int start = row[n], k = cnt[n];
    float a0 = 0, a1 = 0, a2 = 0, a3 = 0, a4 = 0, a5 = 0, a6 = 0, a7 = 0;
    for (int e = slot; e < k; e += 8) {
        int2 rec = srcw[start + e];
        float w = __int_as_float(rec.y);
        const uint4* r4 = (const uint4*)(src + (size_t)rec.x * 32);
        uint4 v = r4[t];
        a0 = fmaf(w, lo2f(v.x), a0); a1 = fmaf(w, hi2f(v.x), a1);
        a2 = fmaf(w, lo2f(v.y), a2); a3 = fmaf(w, hi2f(v.y), a3);
        a4 = fmaf(w, lo2f(v.z), a4); a5 = fmaf(w, hi2f(v.z), a5);
        a6 = fmaf(w, lo2f(v.w), a6); a7 = fmaf(w, hi2f(v.w), a7);
    }
    a0 += __shfl_xor(a0, 8);  a1 += __shfl_xor(a1, 8);
    a2 += __shfl_xor(a2, 8);  a3 += __shfl_xor(a3, 8);
    a4 += __shfl_xor(a4, 8);  a5 += __shfl_xor(a5, 8);
    a6 += __shfl_xor(a6, 8);  a7 += __shfl_xor(a7, 8);
    a0 += __shfl_xor(a0, 16); a1 += __shfl_xor(a1, 16);
    a2 += __shfl_xor(a2, 16); a3 += __shfl_xor(a3, 16);
    a4 += __shfl_xor(a4, 16); a5 += __shfl_xor(a5, 16);
    a6 += __shfl_xor(a6, 16); a7 += __shfl_xor(a7, 16);
    a0 += __shfl_xor(a0, 32); a1 += __shfl_xor(a1, 32);
    a2 += __shfl_xor(a2, 32); a3 += __shfl_xor(a3, 32);
    a4 += __shfl_xor(a4, 32); a5 += __shfl_xor(a5, 32);
    a6 += __shfl_xor(a6, 32); a7 += __shfl_xor(a7, 32);
    if (slot == 0) {
        float dn = -dinv[n];
        uint4 o;
        o.x = pack2(dn * a0, dn * a1);
        o.y = pack2(dn * a2, dn * a3);
        o.z = pack2(dn * a4, dn * a5);
        o.w = pack2(dn * a6, dn * a7);
        ((uint4*)(dst + (size_t)n * 32))[t] = o;
    }
}

// ---------------- MFMA fused input_conv + hidden_conv + GRU gates -----------
// Block = 256 threads = 4 independent waves; wave = 32 nodes (2 M-tiles of 16).
// 16x16x32 bf16 MFMA. A-frag: row=lane&15 (node), k=8*(lane>>4)+j.
// B-frag: col=lane&15 (out ch), same k -> transposed packed weight tables.
// C/D: col=lane&15 (ch), row=(lane>>4)*4+reg (node)  [m89-verified].
__global__ __launch_bounds__(256) void gate_mfma_kernel(
    float* __restrict__ out,
    const float* __restrict__ x,
    const float* __restrict__ h,
    const float* __restrict__ txa,
    const float* __restrict__ txb,
    const unsigned int* __restrict__ t1u,   // bf16 rows: prop(h)
    const unsigned int* __restrict__ ppu,   // bf16 rows: prop(prop(h))
    const float* __restrict__ W1, const float* __restrict__ b1,
    const unsigned int* __restrict__ WT,
    const float* __restrict__ b2, const float* __restrict__ bz,
    const float* __restrict__ br, const float* __restrict__ bc,
    int N) {
    __shared__ unsigned short lds16[4][32][72];   // per-wave 32x64 transpose pad->72

    int tid  = threadIdx.x;
    int lane = tid & 63;
    int wu   = __builtin_amdgcn_readfirstlane(tid >> 6);
    int q    = lane >> 4;      // 0..3
    int r16  = lane & 15;
    int base = blockIdx.x * 128 + wu * 32;

    int nA[2];
    nA[0] = min(base + r16, N - 1);
    nA[1] = min(base + 16 + r16, N - 1);

    const unsigned int* W2eT = WT;
    const unsigned int* WzrT = WT + 6144;
    const unsigned int* WcT  = WT + 14336;

    // ---- ic A-fragments (computed in frag layout on VALU) ----
    uint4 icA[2][2];
    {
        float2 xv[2], tav[2], tbv[2];
        #pragma unroll
        for (int mt = 0; mt < 2; ++mt) {
            xv[mt]  = ((const float2*)x)[nA[mt]];
            tav[mt] = ((const float2*)txa)[nA[mt]];
            tbv[mt] = ((const float2*)txb)[nA[mt]];
        }
        #pragma unroll
        for (int kf = 0; kf < 2; ++kf) {
            int ch0 = kf * 32 + 8 * q;
            float b1s[8], w0[8], w1s[8], w2[8], w3[8], w4[8], w5[8];
            load8(b1 + ch0, b1s);
            load8(W1 + ch0, w0);       load8(W1 + 64 + ch0, w1s);
            load8(W1 + 128 + ch0, w2); load8(W1 + 192 + ch0, w3);
            load8(W1 + 256 + ch0, w4); load8(W1 + 320 + ch0, w5);
            #pragma unroll
            for (int mt = 0; mt < 2; ++mt) {
                float t20 = 2.0f * tbv[mt].x - xv[mt].x;
                float t21 = 2.0f * tbv[mt].y - xv[mt].y;
                unsigned int pr[4];
                #pragma unroll
                for (int p = 0; p < 4; ++p) {
                    float v0 = b1s[2*p]   + xv[mt].x * w0[2*p]   + xv[mt].y * w1s[2*p]
                             + tav[mt].x * w2[2*p]   + tav[mt].y * w3[2*p]
                             + t20 * w4[2*p]   + t21 * w5[2*p];
                    float v1 = b1s[2*p+1] + xv[mt].x * w0[2*p+1] + xv[mt].y * w1s[2*p+1]
                             + tav[mt].x * w2[2*p+1] + tav[mt].y * w3[2*p+1]
                             + t20 * w4[2*p+1] + t21 * w5[2*p+1];
                    pr[p] = pack2(v0, v1);
                }
                icA[mt][kf] = make_uint4(pr[0], pr[1], pr[2], pr[3]);
            }
        }
    }

    // ---- GEMM1: hc = [h|t1|pp] @ W2eff  (K=192, 6 k-steps) ----
    f32x4 acc1[2][4];
    #pragma unroll
    for (int mt = 0; mt < 2; ++mt)
        #pragma unroll
        for (int nt = 0; nt < 4; ++nt)
            acc1[mt][nt] = (f32x4){0.0f, 0.0f, 0.0f, 0.0f};

    #pragma unroll
    for (int ks = 0; ks < 6; ++ks) {
        bf16x8 a[2];
        if (ks < 2) {
            #pragma unroll
            for (int mt = 0; mt < 2; ++mt) {
                float hs[8];
                load8(h + (size_t)nA[mt] * 64 + ks * 32 + 8 * q, hs);
                uint4 u;
                u.x = pack2(hs[0], hs[1]); u.y = pack2(hs[2], hs[3]);
                u.z = pack2(hs[4], hs[5]); u.w = pack2(hs[6], hs[7]);
                a[mt] = asbf(u);
            }
        } else {
            const unsigned int* tab = (ks < 4) ? t1u : ppu;
            int ksl = ks & 1;
            #pragma unroll
            for (int mt = 0; mt < 2; ++mt)
                a[mt] = asbf(*(const uint4*)(tab + (size_t)nA[mt] * 32 + ksl * 16 + q * 4));
        }
        #pragma unroll
        for (int nt = 0; nt < 4; ++nt) {
            bf16x8 b = asbf(*(const uint4*)(W2eT + (nt * 16 + r16) * 96 + ks * 16 + q * 4));
            #pragma unroll
            for (int mt = 0; mt < 2; ++mt)
                acc1[mt][nt] = __builtin_amdgcn_mfma_f32_16x16x32_bf16(a[mt], b, acc1[mt][nt], 0, 0, 0);
        }
    }

    // ---- add b2; transpose hc via per-wave LDS to A-frag layout ----
    float b2v[4];
    #pragma unroll
    for (int nt = 0; nt < 4; ++nt) b2v[nt] = b2[nt * 16 + r16];
    #pragma unroll
    for (int mt = 0; mt < 2; ++mt)
        #pragma unroll
        for (int nt = 0; nt < 4; ++nt)
            #pragma unroll
            for (int reg = 0; reg < 4; ++reg) {
                acc1[mt][nt][reg] += b2v[nt];
                lds16[wu][mt * 16 + 4 * q + reg][nt * 16 + r16] =
                    (unsigned short)bf16r(acc1[mt][nt][reg]);
            }
    __syncthreads();
    bf16x8 hcA[2][2];
    #pragma unroll
    for (int mt = 0; mt < 2; ++mt)
        #pragma unroll
        for (int kf = 0; kf < 2; ++kf)
            hcA[mt][kf] = asbf(*(const uint4*)&lds16[wu][mt * 16 + r16][kf * 32 + 8 * q]);
    __syncthreads();

    // ---- GEMM2: [z|r] = [ic|hc] @ [Wz|Wr]  (K=128, N=128) ----
    f32x4 acc2[2][8];
    #pragma unroll
    for (int mt = 0; mt < 2; ++mt)
        #pragma unroll
        for (int nt = 0; nt < 8; ++nt)
            acc2[mt][nt] = (f32x4){0.0f, 0.0f, 0.0f, 0.0f};

    #pragma unroll
    for (int kf = 0; kf < 4; ++kf) {
        bf16x8 a[2];
        a[0] = (kf < 2) ? asbf(icA[0][kf]) : hcA[0][kf - 2];
        a[1] = (kf < 2) ? asbf(icA[1][kf]) : hcA[1][kf - 2];
        #pragma unroll
        for (int nt = 0; nt < 8; ++nt) {
            bf16x8 b = asbf(*(const uint4*)(WzrT + (nt * 16 + r16) * 64 + kf * 16 + q * 4));
            #pragma unroll
            for (int mt = 0; mt < 2; ++mt)
                acc2[mt][nt] = __builtin_amdgcn_mfma_f32_16x16x32_bf16(a[mt], b, acc2[mt][nt], 0, 0, 0);
        }
    }

    // ---- gates: z = sig(az), r = sig(ar); write r*hc transpose ----
    float bzv[4], brv[4];
    #pragma unroll
    for (int nt = 0; nt < 4; ++nt) { bzv[nt] = bz[nt * 16 + r16]; brv[nt] = br[nt * 16 + r16]; }
    float zz[2][4][4];
    #pragma unroll
    for (int mt = 0; mt < 2; ++mt)
        #pragma unroll
        for (int nt = 0; nt < 4; ++nt)
            #pragma unroll
            for (int reg = 0; reg < 4; ++reg) {
                zz[mt][nt][reg] = 1.0f / (1.0f + __expf(-(acc2[mt][nt][reg] + bzv[nt])));
                float rr = 1.0f / (1.0f + __expf(-(acc2[mt][nt + 4][reg] + brv[nt])));
                float rhc = rr * acc1[mt][nt][reg];
                lds16[wu][mt * 16 + 4 * q + reg][nt * 16 + r16] = (unsigned short)bf16r(rhc);
            }
    __syncthreads();
    bf16x8 rhcA[2][2];
    #pragma unroll
    for (int mt = 0; mt < 2; ++mt)
        #pragma unroll
        for (int kf = 0; kf < 2; ++kf)
            rhcA[mt][kf] = asbf(*(const uint4*)&lds16[wu][mt * 16 + r16][kf * 32 + 8 * q]);

    // ---- GEMM3: cand = [ic|r*hc] @ Wc  (K=128, N=64) ----
    f32x4 acc3[2][4];
    #pragma unroll
    for (int mt = 0; mt < 2; ++mt)
        #pragma unroll
        for (int nt = 0; nt < 4; ++nt)
            acc3[mt][nt] = (f32x4){0.0f, 0.0f, 0.0f, 0.0f};

    #pragma unroll
    for (int kf = 0; kf < 4; ++kf) {
        bf16x8 a[2];
        a[0] = (kf < 2) ? asbf(icA[0][kf]) : rhcA[0][kf - 2];
        a[1] = (kf < 2) ? asbf(icA[1][kf]) : rhcA[1][kf - 2];
        #pragma unroll
        for (int nt = 0; nt < 4; ++nt) {
            bf16x8 b = asbf(*(const uint4*)(WcT + (nt * 16 + r16) * 64 + kf * 16 + q * 4));
            #pragma unroll
            for (int mt = 0; mt < 2; ++mt)
                acc3[mt][nt] = __builtin_amdgcn_mfma_f32_16x16x32_bf16(a[mt], b, acc3[mt][nt], 0, 0, 0);
        }
    }

    // ---- epilogue: out = z*h + (1-z)*tanh(cand + bc) ----
    float bcv[4];
    #pragma unroll
    for (int nt = 0; nt < 4; ++nt) bcv[nt] = bc[nt * 16 + r16];
    #pragma unroll
    for (int mt = 0; mt < 2; ++mt)
        #pragma unroll
        for (int nt = 0; nt < 4; ++nt)
            #pragma unroll
            for (int reg = 0; reg < 4; ++reg) {
                int node = base + mt * 16 + 4 * q + reg;
                if (node < N) {
                    float a = acc3[mt][nt][reg] + bcv[nt];
                    a = fminf(fmaxf(a, -40.0f), 40.0f);
                    float e = __expf(2.0f * a);
                    float ht = 1.0f - 2.0f / (e + 1.0f);
                    float hv = h[(size_t)node * 64 + nt * 16 + r16];
                    float z = zz[mt][nt][reg];
                    out[(size_t)node * 64 + nt * 16 + r16] = z * hv + (1.0f - z) * ht;
                }
            }
}

extern "C" void kernel_launch(void* const* d_in, const int* in_sizes, int n_in,
                              void* d_out, int out_size, void* d_ws, size_t ws_size,
                              hipStream_t stream) {
    const float* x  = (const float*)d_in[0];
    const int*   ei = (const int*)  d_in[1];
    const float* h  = (const float*)d_in[2];
    const float* W1 = (const float*)d_in[3];
    const float* b1 = (const float*)d_in[4];
    const float* W2 = (const float*)d_in[5];
    const float* b2 = (const float*)d_in[6];
    const float* Wz = (const float*)d_in[7];
    const float* bz = (const float*)d_in[8];
    const float* Wr = (const float*)d_in[9];
    const float* br = (const float*)d_in[10];
    const float* Wc = (const float*)d_in[11];
    const float* bc = (const float*)d_in[12];
    float* out = (float*)d_out;

    int N = in_sizes[0] / 2;     // 100000
    int E = in_sizes[1] / 2;     // 1600000
    int NB = (N + 255) / 256;    // scan blocks (391)

    // workspace layout (u32 units):
    char* wsb = (char*)d_ws;
    float* degS = (float*)wsb;                              // N  (memset)
    int*   cnt  = (int*)  (wsb + (size_t)N * 4);            // N  (memset)
    float* dinv = (float*)(wsb + (size_t)2 * N * 4);        // N
    int*   row  = (int*)  (wsb + (size_t)3 * N * 4);        // N
    float* txa  = (float*)(wsb + (size_t)5 * N * 4);        // 2N
    float* txb  = (float*)(wsb + (size_t)7 * N * 4);        // 2N
    int*   bs   = (int*)  (wsb + (size_t)9 * N * 4);        // 1024
    unsigned int* WT = (unsigned int*)(wsb + ((size_t)9 * N + 1024) * 4);   // 18432
    int2*  srcw = (int2*)(wsb + ((size_t)9 * N + 19456) * 4);               // 2E
    unsigned int* bufA = (unsigned int*)(wsb + ((size_t)9 * N + 19456 + 2 * (size_t)E) * 4);  // 32N
    unsigned int* hpp  = (unsigned int*)(wsb + ((size_t)41 * N + 19456 + 2 * (size_t)E) * 4); // 32N
    int*   rank = (int*)(wsb + ((size_t)73 * N + 19456 + 2 * (size_t)E) * 4);                 // E

    // zero only the histogram accumulators
    hipMemsetAsync(wsb, 0, (size_t)2 * N * 4, stream);

    hist_kernel <<<(E + 255) / 256, 256, 0, stream>>>(ei, E, degS, cnt, rank);
    dinv_kernel <<<NB, 256, 0, stream>>>(degS, dinv, N);

    // CSR build: scan cnt -> row; fill is atomic-free via stored ranks
    scanA_kernel<<<NB, 256, 0, stream>>>(cnt, bs, N);
    scanB_kernel<<<1, 1024, 0, stream>>>(bs, NB);
    scanC_kernel<<<NB, 256, 0, stream>>>(cnt, bs, row, N);
    fill_kernel <<<(E + 255) / 256, 256, 0, stream>>>(ei, E, dinv, row, rank, srcw);

    packwT_kernel<<<(18432 + 255) / 256, 256, 0, stream>>>(W2, Wz, Wr, Wc, WT);
    packh_kernel <<<(32 * N + 255) / 256, 256, 0, stream>>>(h, hpp, 32 * N);

    // input path: x -> txa -> txb (2 channels, gather)
    gather2_kernel<<<NB, 256, 0, stream>>>(row, cnt, srcw, dinv, x,   txa, N);
    gather2_kernel<<<NB, 256, 0, stream>>>(row, cnt, srcw, dinv, txa, txb, N);

    // hidden path: hbf -> bufA -> ppbf (monolithic bf16 rows; hpp dual-use)
    int gblocks = (N + 3) / 4;
    gather64_kernel<<<gblocks, 256, 0, stream>>>(row, cnt, srcw, dinv, hpp,  bufA, N);
    gather64_kernel<<<gblocks, 256, 0, stream>>>(row, cnt, srcw, dinv, bufA, hpp,  N);

    // fused MFMA gate (wave = 32 nodes, block = 128 nodes)
    int gateblocks = (N + 127) / 128;
    gate_mfma_kernel<<<gateblocks, 256, 0, stream>>>(
        out, x, h, txa, txb, bufA, hpp, W1, b1, WT, b2, bz, br, bc, N);
}

// Round 9
// 398.391 us; speedup vs baseline: 1.7169x; 1.0174x over previous
//
#include <hip/hip_runtime.h>
#include <hip/hip_bf16.h>
#include <math.h>

#define HID 64

typedef __attribute__((ext_vector_type(8))) short bf16x8;
typedef __attribute__((ext_vector_type(4))) float f32x4;

// ---- bf16 pack/unpack (RNE) ----
__device__ __forceinline__ unsigned int bf16r(float f) {
    unsigned int u = __float_as_uint(f);
    return (u + 0x7fffu + ((u >> 16) & 1u)) >> 16;
}
__device__ __forceinline__ unsigned int pack2(float a, float b) {
    return bf16r(a) | (bf16r(b) << 16);
}
__device__ __forceinline__ float lo2f(unsigned int u) { return __uint_as_float(u << 16); }
__device__ __forceinline__ float hi2f(unsigned int u) { return __uint_as_float(u & 0xffff0000u); }

__device__ __forceinline__ bf16x8 asbf(uint4 u) {
    union { uint4 u4; bf16x8 b; } c; c.u4 = u; return c.b;
}
__device__ __forceinline__ void load8(const float* p, float* d) {
    float4 a = *(const float4*)p, b = *(const float4*)(p + 4);
    d[0]=a.x; d[1]=a.y; d[2]=a.z; d[3]=a.w; d[4]=b.x; d[5]=b.y; d[6]=b.z; d[7]=b.w;
}

// ---------------- XCD-local histograms + per-edge local rank ----------------
// Workgroup-scope atomics on global memory execute at the issuing XCD's L2
// (no sc1) -> atomic across all CUs of that XCD. 8 replicas, one per XCD.
__global__ void hist_kernel(const int* __restrict__ ei, int E,
                            int* __restrict__ degSx, int* __restrict__ cntx,
                            int* __restrict__ rank, int N) {
    unsigned int xcc;
    asm volatile("s_getreg_b32 %0, hwreg(HW_REG_XCC_ID)" : "=s"(xcc));
    xcc &= 7;
    int e = blockIdx.x * blockDim.x + threadIdx.x;
    if (e < E) {
        int s = ei[e], d = ei[E + e];
        __hip_atomic_fetch_add(&degSx[(size_t)xcc * N + s], 1,
                               __ATOMIC_RELAXED, __HIP_MEMORY_SCOPE_WORKGROUP);
        int lr = __hip_atomic_fetch_add(&cntx[(size_t)xcc * N + d], 1,
                                        __ATOMIC_RELAXED, __HIP_MEMORY_SCOPE_WORKGROUP);
        rank[e] = (int)((xcc << 28) | (unsigned int)lr);
    }
}

// ---------------- reduce replicas: dinv, cnt, per-xcd offsets ----------------
__global__ void sumoff_kernel(const int* __restrict__ degSx, const int* __restrict__ cntx,
                              float* __restrict__ dinv, int* __restrict__ cnt,
                              int* __restrict__ off, int N) {
    int n = blockIdx.x * blockDim.x + threadIdx.x;
    if (n >= N) return;
    int dg = 0;
    #pragma unroll
    for (int x = 0; x < 8; ++x) dg += degSx[(size_t)x * N + n];
    dinv[n] = dg > 0 ? rsqrtf((float)dg) : 0.0f;
    int run = 0;
    #pragma unroll
    for (int x = 0; x < 8; ++x) {
        off[(size_t)x * N + n] = run;
        run += cntx[(size_t)x * N + n];
    }
    cnt[n] = run;
}

// ---------------- 3-kernel exclusive scan of cnt -> row ----------------------
__global__ void scanA_kernel(const int* __restrict__ cnt, int* __restrict__ bs, int N) {
    __shared__ int s[256];
    int t = threadIdx.x, n = blockIdx.x * 256 + t;
    s[t] = (n < N) ? cnt[n] : 0;
    __syncthreads();
    for (int off = 128; off > 0; off >>= 1) {
        if (t < off) s[t] += s[t + off];
        __syncthreads();
    }
    if (t == 0) bs[blockIdx.x] = s[0];
}

__global__ void scanB_kernel(int* __restrict__ bs, int nb) {
    __shared__ int s[1024];
    int t = threadIdx.x;
    int orig = (t < nb) ? bs[t] : 0;
    s[t] = orig;
    __syncthreads();
    for (int off = 1; off < 1024; off <<= 1) {
        int v = (t >= off) ? s[t - off] : 0;
        __syncthreads();
        s[t] += v;
        __syncthreads();
    }
    if (t < nb) bs[t] = s[t] - orig;   // exclusive
}

__global__ void scanC_kernel(const int* __restrict__ cnt, const int* __restrict__ bs,
                             int* __restrict__ row, int N) {
    __shared__ int s[256];
    int t = threadIdx.x, n = blockIdx.x * 256 + t;
    int c = (n < N) ? cnt[n] : 0;
    s[t] = c;
    __syncthreads();
    for (int off = 1; off < 256; off <<= 1) {
        int v = (t >= off) ? s[t - off] : 0;
        __syncthreads();
        s[t] += v;
        __syncthreads();
    }
    if (n < N) row[n] = bs[blockIdx.x] + s[t] - c;
}

// ---------------- fill CSR (atomic-free): pos = row + off[xcd] + localrank ---
__global__ void fill_kernel(const int* __restrict__ ei, int E,
                            const float* __restrict__ dinv,
                            const int* __restrict__ row, const int* __restrict__ off,
                            const int* __restrict__ rank,
                            int2* __restrict__ srcw, int N) {
    int e = blockIdx.x * blockDim.x + threadIdx.x;
    if (e < E) {
        int s = ei[e], d = ei[E + e];
        unsigned int r = (unsigned int)rank[e];
        int x  = (int)(r >> 28);
        int lr = (int)(r & 0x0FFFFFFFu);
        int p = row[d] + off[(size_t)x * N + d] + lr;
        srcw[p] = make_int2(s, __float_as_int(dinv[s]));
    }
}

// ---------------- pack transposed bf16 weight tables -------------------------
// WT layout (u32 units):
//   [0,6144):      W2eT[col 0..63][kpair 0..95]   (K=192, eff rows)
//   [6144,14336):  WzrT[col 0..127][kpair 0..63]  (cols 0..63=Wz, 64..127=Wr)
//   [14336,18432): WcT [col 0..63][kpair 0..63]
__global__ void packwT_kernel(const float* __restrict__ W2, const float* __restrict__ Wz,
                              const float* __restrict__ Wr, const float* __restrict__ Wc,
                              unsigned int* __restrict__ WT) {
    int idx = blockIdx.x * blockDim.x + threadIdx.x;
    if (idx >= 18432) return;
    float v0, v1;
    if (idx < 6144) {
        int c = idx / 96, kk = idx % 96;
        int k0 = 2 * kk;
        float a0, a1;
        if (k0 < 64) {
            a0 = W2[k0 * 64 + c] - W2[8192 + k0 * 64 + c];
            a1 = W2[(k0 + 1) * 64 + c] - W2[8192 + (k0 + 1) * 64 + c];
        } else if (k0 < 128) {
            a0 = W2[4096 + (k0 - 64) * 64 + c];
            a1 = W2[4096 + (k0 - 63) * 64 + c];
        } else {
            a0 = 2.0f * W2[8192 + (k0 - 128) * 64 + c];
            a1 = 2.0f * W2[8192 + (k0 - 127) * 64 + c];
        }
        v0 = a0; v1 = a1;
    } else if (idx < 14336) {
        int t = idx - 6144;
        int c = t / 64, kk = t % 64, k0 = 2 * kk;
        const float* Ws = (c < 64) ? Wz : Wr;
        int cc = c & 63;
        v0 = Ws[k0 * 64 + cc];
        v1 = Ws[(k0 + 1) * 64 + cc];
    } else {
        int t = idx - 14336;
        int c = t / 64, kk = t % 64, k0 = 2 * kk;
        v0 = Wc[k0 * 64 + c];
        v1 = Wc[(k0 + 1) * 64 + c];
    }
    WT[idx] = pack2(v0, v1);
}

// ---------------- pack h (fp32) -> monolithic bf16x2 table -------------------
__global__ void packh_kernel(const float* __restrict__ h, unsigned int* __restrict__ hbf,
                             int total2) {
    int i = blockIdx.x * blockDim.x + threadIdx.x;
    if (i < total2) {
        float2 v = ((const float2*)h)[i];
        hbf[i] = pack2(v.x, v.y);
    }
}

// ---------------- 2-channel gather propagation (input path) -----------------
__global__ void gather2_kernel(const int* __restrict__ row, const int* __restrict__ cnt,
                               const int2* __restrict__ srcw, const float* __restrict__ dinv,
                               const float* __restrict__ xsrc, float* __restrict__ dst, int N) {
    int n = blockIdx.x * blockDim.x + threadIdx.x;
    if (n >= N) return;
    int start = row[n], k = cnt[n];
    float a0 = 0.0f, a1 = 0.0f;
    const float2* x2 = (const float2*)xsrc;
    for (int q = 0; q < k; ++q) {
        int2 rec = srcw[start + q];
        float w = __int_as_float(rec.y);
        float2 xv = x2[rec.x];
        a0 = fmaf(w, xv.x, a0);
        a1 = fmaf(w, xv.y, a1);
    }
    float dn = dinv[n];
    dst[2 * n]     = -dn * a0;
    dst[2 * n + 1] = -dn * a1;
}

// ---------------- 64-channel gather propagation, bf16 rows -------------------
__global__ void gather64_kernel(const int* __restrict__ row, const int* __restrict__ cnt,
                                const int2* __restrict__ srcw, const float* __restrict__ dinv,
                                const unsigned int* __restrict__ src,  // bf16 rows, 32 u32/row
                                unsigned int* __restrict__ dst, int N) {
    int wu = __builtin_amdgcn_readfirstlane((int)threadIdx.x >> 6);
    int n = blockIdx.x * 4 + wu;
    if (n >= N) return;
    int lane = threadIdx.x & 63;
    int t    = lane & 7;      // u32 quad within row (channels 8t..8t+7)
    int slot = lane >> 3;     // edge slot 0..7
    int start = row[n], k = cnt[n];
    float a0 = 0, a1 = 0, a2 = 0, a3 = 0, a4 = 0, a5 = 0, a6 = 0, a7 = 0;
    for (int e = slot; e < k; e += 8) {
        int2 rec = srcw[start + e];
        float w = __int_as_float(rec.y);
        const uint4* r4 = (const uint4*)(src + (size_t)rec.x * 32);
        uint4 v = r4[t];
        a0 = fmaf(w, lo2f(v.x), a0); a1 = fmaf(w, hi2f(v.x), a1);
        a2 = fmaf(w, lo2f(v.y), a2); a3 = fmaf(w, hi2f(v.y), a3);
        a4 = fmaf(w, lo2f(v.z), a4); a5 = fmaf(w, hi2f(v.z), a5);
        a6 = fmaf(w, lo2f(v.w), a6); a7 = fmaf(w, hi2f(v.w), a7);
    }
    a0 += __shfl_xor(a0, 8);  a1 += __shfl_xor(a1, 8);
    a2 += __shfl_xor(a2, 8);  a3 += __shfl_xor(a3, 8);
    a4 += __shfl_xor(a4, 8);  a5 += __shfl_xor(a5, 8);
    a6 += __shfl_xor(a6, 8);  a7 += __shfl_xor(a7, 8);
    a0 += __shfl_xor(a0, 16); a1 += __shfl_xor(a1, 16);
    a2 += __shfl_xor(a2, 16); a3 += __shfl_xor(a3, 16);
    a4 += __shfl_xor(a4, 16); a5 += __shfl_xor(a5, 16);
    a6 += __shfl_xor(a6, 16); a7 += __shfl_xor(a7, 16);
    a0 += __shfl_xor(a0, 32); a1 += __shfl_xor(a1, 32);
    a2 += __shfl_xor(a2, 32); a3 += __shfl_xor(a3, 32);
    a4 += __shfl_xor(a4, 32); a5 += __shfl_xor(a5, 32);
    a6 += __shfl_xor(a6, 32); a7 += __shfl_xor(a7, 32);
    if (slot == 0) {
        float dn = -dinv[n];
        uint4 o;
        o.x = pack2(dn * a0, dn * a1);
        o.y = pack2(dn * a2, dn * a3);
        o.z = pack2(dn * a4, dn * a5);
        o.w = pack2(dn * a6, dn * a7);
        ((uint4*)(dst + (size_t)n * 32))[t] = o;
    }
}

// ---------------- MFMA fused input_conv + hidden_conv + GRU gates -----------
// Block = 256 threads = 4 independent waves; wave = 32 nodes (2 M-tiles of 16).
// 16x16x32 bf16 MFMA. A-frag: row=lane&15 (node), k=8*(lane>>4)+j.
// B-frag: col=lane&15 (out ch), same k -> transposed packed weight tables.
// C/D: col=lane&15 (ch), row=(lane>>4)*4+reg (node)  [m89-verified].
__global__ __launch_bounds__(256) void gate_mfma_kernel(
    float* __restrict__ out,
    const float* __restrict__ x,
    const float* __restrict__ h,
    const float* __restrict__ txa,
    const float* __restrict__ txb,
    const unsigned int* __restrict__ t1u,   // bf16 rows: prop(h)
    const unsigned int* __restrict__ ppu,   // bf16 rows: prop(prop(h))
    const float* __restrict__ W1, const float* __restrict__ b1,
    const unsigned int* __restrict__ WT,
    const float* __restrict__ b2, const float* __restrict__ bz,
    const float* __restrict__ br, const float* __restrict__ bc,
    int N) {
    __shared__ unsigned short lds16[4][32][72];   // per-wave 32x64 transpose pad->72

    int tid  = threadIdx.x;
    int lane = tid & 63;
    int wu   = __builtin_amdgcn_readfirstlane(tid >> 6);
    int q    = lane >> 4;      // 0..3
    int r16  = lane & 15;
    int base = blockIdx.x * 128 + wu * 32;

    int nA[2];
    nA[0] = min(base + r16, N - 1);
    nA[1] = min(base + 16 + r16, N - 1);

    const unsigned int* W2eT = WT;
    const unsigned int* WzrT = WT + 6144;
    const unsigned int* WcT  = WT + 14336;

    // ---- ic A-fragments (computed in frag layout on VALU) ----
    uint4 icA[2][2];
    {
        float2 xv[2], tav[2], tbv[2];
        #pragma unroll
        for (int mt = 0; mt < 2; ++mt) {
            xv[mt]  = ((const float2*)x)[nA[mt]];
            tav[mt] = ((const float2*)txa)[nA[mt]];
            tbv[mt] = ((const float2*)txb)[nA[mt]];
        }
        #pragma unroll
        for (int kf = 0; kf < 2; ++kf) {
            int ch0 = kf * 32 + 8 * q;
            float b1s[8], w0[8], w1s[8], w2[8], w3[8], w4[8], w5[8];
            load8(b1 + ch0, b1s);
            load8(W1 + ch0, w0);       load8(W1 + 64 + ch0, w1s);
            load8(W1 + 128 + ch0, w2); load8(W1 + 192 + ch0, w3);
            load8(W1 + 256 + ch0, w4); load8(W1 + 320 + ch0, w5);
            #pragma unroll
            for (int mt = 0; mt < 2; ++mt) {
                float t20 = 2.0f * tbv[mt].x - xv[mt].x;
                float t21 = 2.0f * tbv[mt].y - xv[mt].y;
                unsigned int pr[4];
                #pragma unroll
                for (int p = 0; p < 4; ++p) {
                    float v0 = b1s[2*p]   + xv[mt].x * w0[2*p]   + xv[mt].y * w1s[2*p]
                             + tav[mt].x * w2[2*p]   + tav[mt].y * w3[2*p]
                             + t20 * w4[2*p]   + t21 * w5[2*p];
                    float v1 = b1s[2*p+1] + xv[mt].x * w0[2*p+1] + xv[mt].y * w1s[2*p+1]
                             + tav[mt].x * w2[2*p+1] + tav[mt].y * w3[2*p+1]
                             + t20 * w4[2*p+1] + t21 * w5[2*p+1];
                    pr[p] = pack2(v0, v1);
                }
                icA[mt][kf] = make_uint4(pr[0], pr[1], pr[2], pr[3]);
            }
        }
    }

    // ---- GEMM1: hc = [h|t1|pp] @ W2eff  (K=192, 6 k-steps) ----
    f32x4 acc1[2][4];
    #pragma unroll
    for (int mt = 0; mt < 2; ++mt)
        #pragma unroll
        for (int nt = 0; nt < 4; ++nt)
            acc1[mt][nt] = (f32x4){0.0f, 0.0f, 0.0f, 0.0f};

    #pragma unroll
    for (int ks = 0; ks < 6; ++ks) {
        bf16x8 a[2];
        if (ks < 2) {
            #pragma unroll
            for (int mt = 0; mt < 2; ++mt) {
                float hs[8];
                load8(h + (size_t)nA[mt] * 64 + ks * 32 + 8 * q, hs);
                uint4 u;
                u.x = pack2(hs[0], hs[1]); u.y = pack2(hs[2], hs[3]);
                u.z = pack2(hs[4], hs[5]); u.w = pack2(hs[6], hs[7]);
                a[mt] = asbf(u);
            }
        } else {
            const unsigned int* tab = (ks < 4) ? t1u : ppu;
            int ksl = ks & 1;
            #pragma unroll
            for (int mt = 0; mt < 2; ++mt)
                a[mt] = asbf(*(const uint4*)(tab + (size_t)nA[mt] * 32 + ksl * 16 + q * 4));
        }
        #pragma unroll
        for (int nt = 0; nt < 4; ++nt) {
            bf16x8 b = asbf(*(const uint4*)(W2eT + (nt * 16 + r16) * 96 + ks * 16 + q * 4));
            #pragma unroll
            for (int mt = 0; mt < 2; ++mt)
                acc1[mt][nt] = __builtin_amdgcn_mfma_f32_16x16x32_bf16(a[mt], b, acc1[mt][nt], 0, 0, 0);
        }
    }

    // ---- add b2; transpose hc via per-wave LDS to A-frag layout ----
    float b2v[4];
    #pragma unroll
    for (int nt = 0; nt < 4; ++nt) b2v[nt] = b2[nt * 16 + r16];
    #pragma unroll
    for (int mt = 0; mt < 2; ++mt)
        #pragma unroll
        for (int nt = 0; nt < 4; ++nt)
            #pragma unroll
            for (int reg = 0; reg < 4; ++reg) {
                acc1[mt][nt][reg] += b2v[nt];
                lds16[wu][mt * 16 + 4 * q + reg][nt * 16 + r16] =
                    (unsigned short)bf16r(acc1[mt][nt][reg]);
            }
    __syncthreads();
    bf16x8 hcA[2][2];
    #pragma unroll
    for (int mt = 0; mt < 2; ++mt)
        #pragma unroll
        for (int kf = 0; kf < 2; ++kf)
            hcA[mt][kf] = asbf(*(const uint4*)&lds16[wu][mt * 16 + r16][kf * 32 + 8 * q]);
    __syncthreads();

    // ---- GEMM2: [z|r] = [ic|hc] @ [Wz|Wr]  (K=128, N=128) ----
    f32x4 acc2[2][8];
    #pragma unroll
    for (int mt = 0; mt < 2; ++mt)
        #pragma unroll
        for (int nt = 0; nt < 8; ++nt)
            acc2[mt][nt] = (f32x4){0.0f, 0.0f, 0.0f, 0.0f};

    #pragma unroll
    for (int kf = 0; kf < 4; ++kf) {
        bf16x8 a[2];
        a[0] = (kf < 2) ? asbf(icA[0][kf]) : hcA[0][kf - 2];
        a[1] = (kf < 2) ? asbf(icA[1][kf]) : hcA[1][kf - 2];
        #pragma unroll
        for (int nt = 0; nt < 8; ++nt) {
            bf16x8 b = asbf(*(const uint4*)(WzrT + (nt * 16 + r16) * 64 + kf * 16 + q * 4));
            #pragma unroll
            for (int mt = 0; mt < 2; ++mt)
                acc2[mt][nt] = __builtin_amdgcn_mfma_f32_16x16x32_bf16(a[mt], b, acc2[mt][nt], 0, 0, 0);
        }
    }

    // ---- gates: z = sig(az), r = sig(ar); write r*hc transpose ----
    float bzv[4], brv[4];
    #pragma unroll
    for (int nt = 0; nt < 4; ++nt) { bzv[nt] = bz[nt * 16 + r16]; brv[nt] = br[nt * 16 + r16]; }
    float zz[2][4][4];
    #pragma unroll
    for (int mt = 0; mt < 2; ++mt)
        #pragma unroll
        for (int nt = 0; nt < 4; ++nt)
            #pragma unroll
            for (int reg = 0; reg < 4; ++reg) {
                zz[mt][nt][reg] = 1.0f / (1.0f + __expf(-(acc2[mt][nt][reg] + bzv[nt])));
                float rr = 1.0f / (1.0f + __expf(-(acc2[mt][nt + 4][reg] + brv[nt])));
                float rhc = rr * acc1[mt][nt][reg];
                lds16[wu][mt * 16 + 4 * q + reg][nt * 16 + r16] = (unsigned short)bf16r(rhc);
            }
    __syncthreads();
    bf16x8 rhcA[2][2];
    #pragma unroll
    for (int mt = 0; mt < 2; ++mt)
        #pragma unroll
        for (int kf = 0; kf < 2; ++kf)
            rhcA[mt][kf] = asbf(*(const uint4*)&lds16[wu][mt * 16 + r16][kf * 32 + 8 * q]);

    // ---- GEMM3: cand = [ic|r*hc] @ Wc  (K=128, N=64) ----
    f32x4 acc3[2][4];
    #pragma unroll
    for (int mt = 0; mt < 2; ++mt)
        #pragma unroll
        for (int nt = 0; nt < 4; ++nt)
            acc3[mt][nt] = (f32x4){0.0f, 0.0f, 0.0f, 0.0f};

    #pragma unroll
    for (int kf = 0; kf < 4; ++kf) {
        bf16x8 a[2];
        a[0] = (kf < 2) ? asbf(icA[0][kf]) : rhcA[0][kf - 2];
        a[1] = (kf < 2) ? asbf(icA[1][kf]) : rhcA[1][kf - 2];
        #pragma unroll
        for (int nt = 0; nt < 4; ++nt) {
            bf16x8 b = asbf(*(const uint4*)(WcT + (nt * 16 + r16) * 64 + kf * 16 + q * 4));
            #pragma unroll
            for (int mt = 0; mt < 2; ++mt)
                acc3[mt][nt] = __builtin_amdgcn_mfma_f32_16x16x32_bf16(a[mt], b, acc3[mt][nt], 0, 0, 0);
        }
    }

    // ---- epilogue: out = z*h + (1-z)*tanh(cand + bc) ----
    float bcv[4];
    #pragma unroll
    for (int nt = 0; nt < 4; ++nt) bcv[nt] = bc[nt * 16 + r16];
    #pragma unroll
    for (int mt = 0; mt < 2; ++mt)
        #pragma unroll
        for (int nt = 0; nt < 4; ++nt)
            #pragma unroll
            for (int reg = 0; reg < 4; ++reg) {
                int node = base + mt * 16 + 4 * q + reg;
                if (node < N) {
                    float a = acc3[mt][nt][reg] + bcv[nt];
                    a = fminf(fmaxf(a, -40.0f), 40.0f);
                    float e = __expf(2.0f * a);
                    float ht = 1.0f - 2.0f / (e + 1.0f);
                    float hv = h[(size_t)node * 64 + nt * 16 + r16];
                    float z = zz[mt][nt][reg];
                    out[(size_t)node * 64 + nt * 16 + r16] = z * hv + (1.0f - z) * ht;
                }
            }
}

extern "C" void kernel_launch(void* const* d_in, const int* in_sizes, int n_in,
                              void* d_out, int out_size, void* d_ws, size_t ws_size,
                              hipStream_t stream) {
    const float* x  = (const float*)d_in[0];
    const int*   ei = (const int*)  d_in[1];
    const float* h  = (const float*)d_in[2];
    const float* W1 = (const float*)d_in[3];
    const float* b1 = (const float*)d_in[4];
    const float* W2 = (const float*)d_in[5];
    const float* b2 = (const float*)d_in[6];
    const float* Wz = (const float*)d_in[7];
    const float* bz = (const float*)d_in[8];
    const float* Wr = (const float*)d_in[9];
    const float* br = (const float*)d_in[10];
    const float* Wc = (const float*)d_in[11];
    const float* bc = (const float*)d_in[12];
    float* out = (float*)d_out;

    int N = in_sizes[0] / 2;     // 100000
    int E = in_sizes[1] / 2;     // 1600000
    int NB = (N + 255) / 256;    // scan blocks (391)

    // workspace layout (u32 units):
    //   perm: dinv N | row N | cnt N | txa 2N | txb 2N | bs 1024 | WT 18432 | srcw 2E
    //   O = 7N+19456+2E: bufA 32N | hpp 32N   (total 71N+19456+2E u32 ~= 41.3 MB)
    //   temp aliases in [O, O+64N): degSx 8N | cntx 8N | off 8N | rank E
    //   (hist/sumoff/fill consume temps before bufA/hpp/packh writes overlap them)
    char* wsb = (char*)d_ws;
    float* dinv = (float*)wsb;                                   // N
    int*   row  = (int*)  (wsb + (size_t)N * 4);                 // N
    int*   cnt  = (int*)  (wsb + (size_t)2 * N * 4);             // N
    float* txa  = (float*)(wsb + (size_t)3 * N * 4);             // 2N
    float* txb  = (float*)(wsb + (size_t)5 * N * 4);             // 2N
    int*   bs   = (int*)  (wsb + (size_t)7 * N * 4);             // 1024
    unsigned int* WT = (unsigned int*)(wsb + ((size_t)7 * N + 1024) * 4);    // 18432
    int2*  srcw = (int2*)(wsb + ((size_t)7 * N + 19456) * 4);                // 2E
    size_t O = (size_t)7 * N + 19456 + 2 * (size_t)E;
    unsigned int* bufA  = (unsigned int*)(wsb + O * 4);                      // 32N
    unsigned int* hpp   = (unsigned int*)(wsb + (O + (size_t)32 * N) * 4);   // 32N
    int*   degSx = (int*)(wsb + O * 4);                                      // 8N (alias)
    int*   cntx  = (int*)(wsb + (O + (size_t)8 * N) * 4);                    // 8N (alias)
    int*   off   = (int*)(wsb + (O + (size_t)16 * N) * 4);                   // 8N (alias)
    int*   rank  = (int*)(wsb + (O + (size_t)24 * N) * 4);                   // E  (alias)

    // zero the 16 replica histograms (6.4 MB)
    hipMemsetAsync(degSx, 0, (size_t)16 * N * 4, stream);

    hist_kernel  <<<(E + 255) / 256, 256, 0, stream>>>(ei, E, degSx, cntx, rank, N);
    sumoff_kernel<<<NB, 256, 0, stream>>>(degSx, cntx, dinv, cnt, off, N);

    // CSR build: scan cnt -> row; fill is atomic-free via xcd-local ranks
    scanA_kernel<<<NB, 256, 0, stream>>>(cnt, bs, N);
    scanB_kernel<<<1, 1024, 0, stream>>>(bs, NB);
    scanC_kernel<<<NB, 256, 0, stream>>>(cnt, bs, row, N);
    fill_kernel <<<(E + 255) / 256, 256, 0, stream>>>(ei, E, dinv, row, off, rank, srcw, N);

    // packs (must run after fill: hpp overlaps rank tail)
    packwT_kernel<<<(18432 + 255) / 256, 256, 0, stream>>>(W2, Wz, Wr, Wc, WT);
    packh_kernel <<<(32 * N + 255) / 256, 256, 0, stream>>>(h, hpp, 32 * N);

    // input path: x -> txa -> txb (2 channels, gather)
    gather2_kernel<<<NB, 256, 0, stream>>>(row, cnt, srcw, dinv, x,   txa, N);
    gather2_kernel<<<NB, 256, 0, stream>>>(row, cnt, srcw, dinv, txa, txb, N);

    // hidden path: hbf -> bufA -> ppbf (monolithic bf16 rows; hpp dual-use)
    int gblocks = (N + 3) / 4;
    gather64_kernel<<<gblocks, 256, 0, stream>>>(row, cnt, srcw, dinv, hpp,  bufA, N);
    gather64_kernel<<<gblocks, 256, 0, stream>>>(row, cnt, srcw, dinv, bufA, hpp,  N);

    // fused MFMA gate (wave = 32 nodes, block = 128 nodes)
    int gateblocks = (N + 127) / 128;
    gate_mfma_kernel<<<gateblocks, 256, 0, stream>>>(
        out, x, h, txa, txb, bufA, hpp, W1, b1, WT, b2, bz, br, bc, N);
}

// Round 10
// 277.954 us; speedup vs baseline: 2.4608x; 1.4333x over previous
//
#include <hip/hip_runtime.h>
#include <hip/hip_bf16.h>
#include <math.h>

#define HID 64
#define NBA 512        // phase A/B blocks
#define NBUCK 256      // buckets (key>>9)
#define BSHIFT 9
#define BINS 512       // nodes per bucket
#define NBN (NBUCK * NBA)   // 131072 counters per side

typedef __attribute__((ext_vector_type(8))) short bf16x8;
typedef __attribute__((ext_vector_type(4))) float f32x4;

// ---- bf16 pack/unpack (RNE) ----
__device__ __forceinline__ unsigned int bf16r(float f) {
    unsigned int u = __float_as_uint(f);
    return (u + 0x7fffu + ((u >> 16) & 1u)) >> 16;
}
__device__ __forceinline__ unsigned int pack2(float a, float b) {
    return bf16r(a) | (bf16r(b) << 16);
}
__device__ __forceinline__ float lo2f(unsigned int u) { return __uint_as_float(u << 16); }
__device__ __forceinline__ float hi2f(unsigned int u) { return __uint_as_float(u & 0xffff0000u); }

__device__ __forceinline__ bf16x8 asbf(uint4 u) {
    union { uint4 u4; bf16x8 b; } c; c.u4 = u; return c.b;
}
__device__ __forceinline__ void load8(const float* p, float* d) {
    float4 a = *(const float4*)p, b = *(const float4*)(p + 4);
    d[0]=a.x; d[1]=a.y; d[2]=a.z; d[3]=a.w; d[4]=b.x; d[5]=b.y; d[6]=b.z; d[7]=b.w;
}

// ---------------- phase A: per-block bucket counts (LDS only) ----------------
__global__ void bucketA_kernel(const int* __restrict__ ei, int E,
                               int* __restrict__ cntsc) {
    __shared__ int cd[NBUCK], cs[NBUCK];
    int t = threadIdx.x;
    cd[t] = 0; cs[t] = 0;
    __syncthreads();
    int ce = (E + NBA - 1) / NBA;
    int e0 = blockIdx.x * ce, e1 = min(e0 + ce, E);
    for (int e = e0 + t; e < e1; e += 256) {
        int s = ei[e], d = ei[E + e];
        atomicAdd(&cs[s >> BSHIFT], 1);
        atomicAdd(&cd[d >> BSHIFT], 1);
    }
    __syncthreads();
    cntsc[t * NBA + blockIdx.x]       = cd[t];   // dst side [0, NBN)
    cntsc[NBN + t * NBA + blockIdx.x] = cs[t];   // src side [NBN, 2*NBN)
}

// ---------------- 3-kernel exclusive scan (generic, n = 2*NBN) ---------------
__global__ void scanA_kernel(const int* __restrict__ cnt, int* __restrict__ bs, int N) {
    __shared__ int s[256];
    int t = threadIdx.x, n = blockIdx.x * 256 + t;
    s[t] = (n < N) ? cnt[n] : 0;
    __syncthreads();
    for (int off = 128; off > 0; off >>= 1) {
        if (t < off) s[t] += s[t + off];
        __syncthreads();
    }
    if (t == 0) bs[blockIdx.x] = s[0];
}

__global__ void scanB_kernel(int* __restrict__ bs, int nb) {
    __shared__ int s[1024];
    int t = threadIdx.x;
    int orig = (t < nb) ? bs[t] : 0;
    s[t] = orig;
    __syncthreads();
    for (int off = 1; off < 1024; off <<= 1) {
        int v = (t >= off) ? s[t - off] : 0;
        __syncthreads();
        s[t] += v;
        __syncthreads();
    }
    if (t < nb) bs[t] = s[t] - orig;   // exclusive
}

__global__ void scanC_kernel(const int* __restrict__ cnt, const int* __restrict__ bs,
                             int* __restrict__ outp, int N) {
    __shared__ int s[256];
    int t = threadIdx.x, n = blockIdx.x * 256 + t;
    int c = (n < N) ? cnt[n] : 0;
    s[t] = c;
    __syncthreads();
    for (int off = 1; off < 256; off <<= 1) {
        int v = (t >= off) ? s[t - off] : 0;
        __syncthreads();
        s[t] += v;
        __syncthreads();
    }
    if (n < N) outp[n] = bs[blockIdx.x] + s[t] - c;
}

// ---------------- phase B: scatter records into bucket regions ---------------
__global__ void bucketB_kernel(const int* __restrict__ ei, int E,
                               const int* __restrict__ scanned,
                               int2* __restrict__ dstrec, int* __restrict__ srckeys) {
    __shared__ int cd[NBUCK], cs[NBUCK], bd[NBUCK], bsr[NBUCK];
    int t = threadIdx.x;
    cd[t] = 0; cs[t] = 0;
    bd[t]  = scanned[t * NBA + blockIdx.x];
    bsr[t] = scanned[NBN + t * NBA + blockIdx.x] - E;
    __syncthreads();
    int ce = (E + NBA - 1) / NBA;
    int e0 = blockIdx.x * ce, e1 = min(e0 + ce, E);
    for (int e = e0 + t; e < e1; e += 256) {
        int s = ei[e], d = ei[E + e];
        int db = d >> BSHIFT, sb = s >> BSHIFT;
        int rd = atomicAdd(&cd[db], 1);
        dstrec[bd[db] + rd] = make_int2(d, s);
        int rs = atomicAdd(&cs[sb], 1);
        srckeys[bsr[sb] + rs] = s;
    }
}

// ---------------- phase C2: per-bucket src counts -> dinv --------------------
__global__ void bucketC2_kernel(const int* __restrict__ srckeys,
                                const int* __restrict__ scanned,
                                float* __restrict__ dinv, int N, int E) {
    __shared__ int deg[BINS];
    int b = blockIdx.x, t = threadIdx.x;   // 512 threads
    deg[t] = 0;
    __syncthreads();
    int start = scanned[NBN + b * NBA] - E;
    int end   = (b < NBUCK - 1) ? scanned[NBN + (b + 1) * NBA] - E : E;
    for (int i = start + t; i < end; i += BINS)
        atomicAdd(&deg[srckeys[i] & (BINS - 1)], 1);
    __syncthreads();
    int node = (b << BSHIFT) + t;
    if (node < N) {
        int dg = deg[t];
        dinv[node] = dg > 0 ? rsqrtf((float)dg) : 0.0f;
    }
}

// ---------------- phase C1: per-bucket CSR (row, cnt, srcw) ------------------
__global__ void bucketC1_kernel(const int2* __restrict__ dstrec,
                                const int* __restrict__ scanned,
                                const float* __restrict__ dinv,
                                int* __restrict__ row, int* __restrict__ cnt,
                                int2* __restrict__ srcw, int N, int E) {
    __shared__ int lc[BINS], ls[BINS], lr[BINS];
    int b = blockIdx.x, t = threadIdx.x;   // 512 threads
    lc[t] = 0; lr[t] = 0;
    __syncthreads();
    int start = scanned[b * NBA];
    int end   = (b < NBUCK - 1) ? scanned[(b + 1) * NBA] : E;
    for (int i = start + t; i < end; i += BINS)
        atomicAdd(&lc[dstrec[i].x & (BINS - 1)], 1);
    __syncthreads();
    // inclusive scan of lc (Hillis-Steele, 512 threads)
    ls[t] = lc[t];
    __syncthreads();
    for (int off = 1; off < BINS; off <<= 1) {
        int v = (t >= off) ? ls[t - off] : 0;
        __syncthreads();
        ls[t] += v;
        __syncthreads();
    }
    int rl = start + ls[t] - lc[t];   // exclusive -> global row
    int node = (b << BSHIFT) + t;
    if (node < N) { row[node] = rl; cnt[node] = lc[t]; }
    __syncthreads();
    ls[t] = rl;                        // reuse as scatter base
    __syncthreads();
    for (int i = start + t; i < end; i += BINS) {
        int2 rec = dstrec[i];
        int bin = rec.x & (BINS - 1);
        int p = ls[bin] + atomicAdd(&lr[bin], 1);
        srcw[p] = make_int2(rec.y, __float_as_int(dinv[rec.y]));
    }
}

// ---------------- pack transposed bf16 weight tables -------------------------
__global__ void packwT_kernel(const float* __restrict__ W2, const float* __restrict__ Wz,
                              const float* __restrict__ Wr, const float* __restrict__ Wc,
                              unsigned int* __restrict__ WT) {
    int idx = blockIdx.x * blockDim.x + threadIdx.x;
    if (idx >= 18432) return;
    float v0, v1;
    if (idx < 6144) {
        int c = idx / 96, kk = idx % 96;
        int k0 = 2 * kk;
        if (k0 < 64) {
            v0 = W2[k0 * 64 + c] - W2[8192 + k0 * 64 + c];
            v1 = W2[(k0 + 1) * 64 + c] - W2[8192 + (k0 + 1) * 64 + c];
        } else if (k0 < 128) {
            v0 = W2[4096 + (k0 - 64) * 64 + c];
            v1 = W2[4096 + (k0 - 63) * 64 + c];
        } else {
            v0 = 2.0f * W2[8192 + (k0 - 128) * 64 + c];
            v1 = 2.0f * W2[8192 + (k0 - 127) * 64 + c];
        }
    } else if (idx < 14336) {
        int t = idx - 6144;
        int c = t / 64, kk = t % 64, k0 = 2 * kk;
        const float* Ws = (c < 64) ? Wz : Wr;
        int cc = c & 63;
        v0 = Ws[k0 * 64 + cc];
        v1 = Ws[(k0 + 1) * 64 + cc];
    } else {
        int t = idx - 14336;
        int c = t / 64, kk = t % 64, k0 = 2 * kk;
        v0 = Wc[k0 * 64 + c];
        v1 = Wc[(k0 + 1) * 64 + c];
    }
    WT[idx] = pack2(v0, v1);
}

// ---------------- pack h (fp32) -> monolithic bf16x2 table -------------------
__global__ void packh_kernel(const float* __restrict__ h, unsigned int* __restrict__ hbf,
                             int total2) {
    int i = blockIdx.x * blockDim.x + threadIdx.x;
    if (i < total2) {
        float2 v = ((const float2*)h)[i];
        hbf[i] = pack2(v.x, v.y);
    }
}

// ---------------- 2-channel gather propagation (input path) -----------------
__global__ void gather2_kernel(const int* __restrict__ row, const int* __restrict__ cnt,
                               const int2* __restrict__ srcw, const float* __restrict__ dinv,
                               const float* __restrict__ xsrc, float* __restrict__ dst, int N) {
    int n = blockIdx.x * blockDim.x + threadIdx.x;
    if (n >= N) return;
    int start = row[n], k = cnt[n];
    float a0 = 0.0f, a1 = 0.0f;
    const float2* x2 = (const float2*)xsrc;
    for (int q = 0; q < k; ++q) {
        int2 rec = srcw[start + q];
        float w = __int_as_float(rec.y);
        float2 xv = x2[rec.x];
        a0 = fmaf(w, xv.x, a0);
        a1 = fmaf(w, xv.y, a1);
    }
    float dn = dinv[n];
    dst[2 * n]     = -dn * a0;
    dst[2 * n + 1] = -dn * a1;
}

// ---------------- 64-channel gather propagation, bf16 rows -------------------
__global__ void gather64_kernel(const int* __restrict__ row, const int* __restrict__ cnt,
                                const int2* __restrict__ srcw, const float* __restrict__ dinv,
                                const unsigned int* __restrict__ src,  // bf16 rows, 32 u32/row
                                unsigned int* __restrict__ dst, int N) {
    int wu = __builtin_amdgcn_readfirstlane((int)threadIdx.x >> 6);
    int n = blockIdx.x * 4 + wu;
    if (n >= N) return;
    int lane = threadIdx.x & 63;
    int t    = lane & 7;      // u32 quad within row (channels 8t..8t+7)
    int slot = lane >> 3;     // edge slot 0..7
    int start = row[n], k = cnt[n];
    float a0 = 0, a1 = 0, a2 = 0, a3 = 0, a4 = 0, a5 = 0, a6 = 0, a7 = 0;
    for (int e = slot; e < k; e += 8) {
        int2 rec = srcw[start + e];
        float w = __int_as_float(rec.y);
        const uint4* r4 = (const uint4*)(src + (size_t)rec.x * 32);
        uint4 v = r4[t];
        a0 = fmaf(w, lo2f(v.x), a0); a1 = fmaf(w, hi2f(v.x), a1);
        a2 = fmaf(w, lo2f(v.y), a2); a3 = fmaf(w, hi2f(v.y), a3);
        a4 = fmaf(w, lo2f(v.z), a4); a5 = fmaf(w, hi2f(v.z), a5);
        a6 = fmaf(w, lo2f(v.w), a6); a7 = fmaf(w, hi2f(v.w), a7);
    }
    a0 += __shfl_xor(a0, 8);  a1 += __shfl_xor(a1, 8);
    a2 += __shfl_xor(a2, 8);  a3 += __shfl_xor(a3, 8);
    a4 += __shfl_xor(a4, 8);  a5 += __shfl_xor(a5, 8);
    a6 += __shfl_xor(a6, 8);  a7 += __shfl_xor(a7, 8);
    a0 += __shfl_xor(a0, 16); a1 += __shfl_xor(a1, 16);
    a2 += __shfl_xor(a2, 16); a3 += __shfl_xor(a3, 16);
    a4 += __shfl_xor(a4, 16); a5 += __shfl_xor(a5, 16);
    a6 += __shfl_xor(a6, 16); a7 += __shfl_xor(a7, 16);
    a0 += __shfl_xor(a0, 32); a1 += __shfl_xor(a1, 32);
    a2 += __shfl_xor(a2, 32); a3 += __shfl_xor(a3, 32);
    a4 += __shfl_xor(a4, 32); a5 += __shfl_xor(a5, 32);
    a6 += __shfl_xor(a6, 32); a7 += __shfl_xor(a7, 32);
    if (slot == 0) {
        float dn = -dinv[n];
        uint4 o;
        o.x = pack2(dn * a0, dn * a1);
        o.y = pack2(dn * a2, dn * a3);
        o.z = pack2(dn * a4, dn * a5);
        o.w = pack2(dn * a6, dn * a7);
        ((uint4*)(dst + (size_t)n * 32))[t] = o;
    }
}

// ---------------- MFMA fused input_conv + hidden_conv + GRU gates -----------
__global__ __launch_bounds__(256) void gate_mfma_kernel(
    float* __restrict__ out,
    const float* __restrict__ x,
    const float* __restrict__ h,
    const float* __restrict__ txa,
    const float* __restrict__ txb,
    const unsigned int* __restrict__ t1u,   // bf16 rows: prop(h)
    const unsigned int* __restrict__ ppu,   // bf16 rows: prop(prop(h))
    const float* __restrict__ W1, const float* __restrict__ b1,
    const unsigned int* __restrict__ WT,
    const float* __restrict__ b2, const float* __restrict__ bz,
    const float* __restrict__ br, const float* __restrict__ bc,
    int N) {
    __shared__ unsigned short lds16[4][32][72];   // per-wave 32x64 transpose pad->72

    int tid  = threadIdx.x;
    int lane = tid & 63;
    int wu   = __builtin_amdgcn_readfirstlane(tid >> 6);
    int q    = lane >> 4;      // 0..3
    int r16  = lane & 15;
    int base = blockIdx.x * 128 + wu * 32;

    int nA[2];
    nA[0] = min(base + r16, N - 1);
    nA[1] = min(base + 16 + r16, N - 1);

    const unsigned int* W2eT = WT;
    const unsigned int* WzrT = WT + 6144;
    const unsigned int* WcT  = WT + 14336;

    // ---- ic A-fragments (computed in frag layout on VALU) ----
    uint4 icA[2][2];
    {
        float2 xv[2], tav[2], tbv[2];
        #pragma unroll
        for (int mt = 0; mt < 2; ++mt) {
            xv[mt]  = ((const float2*)x)[nA[mt]];
            tav[mt] = ((const float2*)txa)[nA[mt]];
            tbv[mt] = ((const float2*)txb)[nA[mt]];
        }
        #pragma unroll
        for (int kf = 0; kf < 2; ++kf) {
            int ch0 = kf * 32 + 8 * q;
            float b1s[8], w0[8], w1s[8], w2[8], w3[8], w4[8], w5[8];
            load8(b1 + ch0, b1s);
            load8(W1 + ch0, w0);       load8(W1 + 64 + ch0, w1s);
            load8(W1 + 128 + ch0, w2); load8(W1 + 192 + ch0, w3);
            load8(W1 + 256 + ch0, w4); load8(W1 + 320 + ch0, w5);
            #pragma unroll
            for (int mt = 0; mt < 2; ++mt) {
                float t20 = 2.0f * tbv[mt].x - xv[mt].x;
                float t21 = 2.0f * tbv[mt].y - xv[mt].y;
                unsigned int pr[4];
                #pragma unroll
                for (int p = 0; p < 4; ++p) {
                    float v0 = b1s[2*p]   + xv[mt].x * w0[2*p]   + xv[mt].y * w1s[2*p]
                             + tav[mt].x * w2[2*p]   + tav[mt].y * w3[2*p]
                             + t20 * w4[2*p]   + t21 * w5[2*p];
                    float v1 = b1s[2*p+1] + xv[mt].x * w0[2*p+1] + xv[mt].y * w1s[2*p+1]
                             + tav[mt].x * w2[2*p+1] + tav[mt].y * w3[2*p+1]
                             + t20 * w4[2*p+1] + t21 * w5[2*p+1];
                    pr[p] = pack2(v0, v1);
                }
                icA[mt][kf] = make_uint4(pr[0], pr[1], pr[2], pr[3]);
            }
        }
    }

    // ---- GEMM1: hc = [h|t1|pp] @ W2eff  (K=192, 6 k-steps) ----
    f32x4 acc1[2][4];
    #pragma unroll
    for (int mt = 0; mt < 2; ++mt)
        #pragma unroll
        for (int nt = 0; nt < 4; ++nt)
            acc1[mt][nt] = (f32x4){0.0f, 0.0f, 0.0f, 0.0f};

    #pragma unroll
    for (int ks = 0; ks < 6; ++ks) {
        bf16x8 a[2];
        if (ks < 2) {
            #pragma unroll
            for (int mt = 0; mt < 2; ++mt) {
                float hs[8];
                load8(h + (size_t)nA[mt] * 64 + ks * 32 + 8 * q, hs);
                uint4 u;
                u.x = pack2(hs[0], hs[1]); u.y = pack2(hs[2], hs[3]);
                u.z = pack2(hs[4], hs[5]); u.w = pack2(hs[6], hs[7]);
                a[mt] = asbf(u);
            }
        } else {
            const unsigned int* tab = (ks < 4) ? t1u : ppu;
            int ksl = ks & 1;
            #pragma unroll
            for (int mt = 0; mt < 2; ++mt)
                a[mt] = asbf(*(const uint4*)(tab + (size_t)nA[mt] * 32 + ksl * 16 + q * 4));
        }
        #pragma unroll
        for (int nt = 0; nt < 4; ++nt) {
            bf16x8 b = asbf(*(const uint4*)(W2eT + (nt * 16 + r16) * 96 + ks * 16 + q * 4));
            #pragma unroll
            for (int mt = 0; mt < 2; ++mt)
                acc1[mt][nt] = __builtin_amdgcn_mfma_f32_16x16x32_bf16(a[mt], b, acc1[mt][nt], 0, 0, 0);
        }
    }

    // ---- add b2; transpose hc via per-wave LDS to A-frag layout ----
    float b2v[4];
    #pragma unroll
    for (int nt = 0; nt < 4; ++nt) b2v[nt] = b2[nt * 16 + r16];
    #pragma unroll
    for (int mt = 0; mt < 2; ++mt)
        #pragma unroll
        for (int nt = 0; nt < 4; ++nt)
            #pragma unroll
            for (int reg = 0; reg < 4; ++reg) {
                acc1[mt][nt][reg] += b2v[nt];
                lds16[wu][mt * 16 + 4 * q + reg][nt * 16 + r16] =
                    (unsigned short)bf16r(acc1[mt][nt][reg]);
            }
    __syncthreads();
    bf16x8 hcA[2][2];
    #pragma unroll
    for (int mt = 0; mt < 2; ++mt)
        #pragma unroll
        for (int kf = 0; kf < 2; ++kf)
            hcA[mt][kf] = asbf(*(const uint4*)&lds16[wu][mt * 16 + r16][kf * 32 + 8 * q]);
    __syncthreads();

    // ---- GEMM2: [z|r] = [ic|hc] @ [Wz|Wr]  (K=128, N=128) ----
    f32x4 acc2[2][8];
    #pragma unroll
    for (int mt = 0; mt < 2; ++mt)
        #pragma unroll
        for (int nt = 0; nt < 8; ++nt)
            acc2[mt][nt] = (f32x4){0.0f, 0.0f, 0.0f, 0.0f};

    #pragma unroll
    for (int kf = 0; kf < 4; ++kf) {
        bf16x8 a[2];
        a[0] = (kf < 2) ? asbf(icA[0][kf]) : hcA[0][kf - 2];
        a[1] = (kf < 2) ? asbf(icA[1][kf]) : hcA[1][kf - 2];
        #pragma unroll
        for (int nt = 0; nt < 8; ++nt) {
            bf16x8 b = asbf(*(const uint4*)(WzrT + (nt * 16 + r16) * 64 + kf * 16 + q * 4));
            #pragma unroll
            for (int mt = 0; mt < 2; ++mt)
                acc2[mt][nt] = __builtin_amdgcn_mfma_f32_16x16x32_bf16(a[mt], b, acc2[mt][nt], 0, 0, 0);
        }
    }

    // ---- gates: z = sig(az), r = sig(ar); write r*hc transpose ----
    float bzv[4], brv[4];
    #pragma unroll
    for (int nt = 0; nt < 4; ++nt) { bzv[nt] = bz[nt * 16 + r16]; brv[nt] = br[nt * 16 + r16]; }
    float zz[2][4][4];
    #pragma unroll
    for (int mt = 0; mt < 2; ++mt)
        #pragma unroll
        for (int nt = 0; nt < 4; ++nt)
            #pragma unroll
            for (int reg = 0; reg < 4; ++reg) {
                zz[mt][nt][reg] = 1.0f / (1.0f + __expf(-(acc2[mt][nt][reg] + bzv[nt])));
                float rr = 1.0f / (1.0f + __expf(-(acc2[mt][nt + 4][reg] + brv[nt])));
                float rhc = rr * acc1[mt][nt][reg];
                lds16[wu][mt * 16 + 4 * q + reg][nt * 16 + r16] = (unsigned short)bf16r(rhc);
            }
    __syncthreads();
    bf16x8 rhcA[2][2];
    #pragma unroll
    for (int mt = 0; mt < 2; ++mt)
        #pragma unroll
        for (int kf = 0; kf < 2; ++kf)
            rhcA[mt][kf] = asbf(*(const uint4*)&lds16[wu][mt * 16 + r16][kf * 32 + 8 * q]);

    // ---- GEMM3: cand = [ic|r*hc] @ Wc  (K=128, N=64) ----
    f32x4 acc3[2][4];
    #pragma unroll
    for (int mt = 0; mt < 2; ++mt)
        #pragma unroll
        for (int nt = 0; nt < 4; ++nt)
            acc3[mt][nt] = (f32x4){0.0f, 0.0f, 0.0f, 0.0f};

    #pragma unroll
    for (int kf = 0; kf < 4; ++kf) {
        bf16x8 a[2];
        a[0] = (kf < 2) ? asbf(icA[0][kf]) : rhcA[0][kf - 2];
        a[1] = (kf < 2) ? asbf(icA[1][kf]) : rhcA[1][kf - 2];
        #pragma unroll
        for (int nt = 0; nt < 4; ++nt) {
            bf16x8 b = asbf(*(const uint4*)(WcT + (nt * 16 + r16) * 64 + kf * 16 + q * 4));
            #pragma unroll
            for (int mt = 0; mt < 2; ++mt)
                acc3[mt][nt] = __builtin_amdgcn_mfma_f32_16x16x32_bf16(a[mt], b, acc3[mt][nt], 0, 0, 0);
        }
    }

    // ---- epilogue: out = z*h + (1-z)*tanh(cand + bc) ----
    float bcv[4];
    #pragma unroll
    for (int nt = 0; nt < 4; ++nt) bcv[nt] = bc[nt * 16 + r16];
    #pragma unroll
    for (int mt = 0; mt < 2; ++mt)
        #pragma unroll
        for (int nt = 0; nt < 4; ++nt)
            #pragma unroll
            for (int reg = 0; reg < 4; ++reg) {
                int node = base + mt * 16 + 4 * q + reg;
                if (node < N) {
                    float a = acc3[mt][nt][reg] + bcv[nt];
                    a = fminf(fmaxf(a, -40.0f), 40.0f);
                    float e = __expf(2.0f * a);
                    float ht = 1.0f - 2.0f / (e + 1.0f);
                    float hv = h[(size_t)node * 64 + nt * 16 + r16];
                    float z = zz[mt][nt][reg];
                    out[(size_t)node * 64 + nt * 16 + r16] = z * hv + (1.0f - z) * ht;
                }
            }
}

extern "C" void kernel_launch(void* const* d_in, const int* in_sizes, int n_in,
                              void* d_out, int out_size, void* d_ws, size_t ws_size,
                              hipStream_t stream) {
    const float* x  = (const float*)d_in[0];
    const int*   ei = (const int*)  d_in[1];
    const float* h  = (const float*)d_in[2];
    const float* W1 = (const float*)d_in[3];
    const float* b1 = (const float*)d_in[4];
    const float* W2 = (const float*)d_in[5];
    const float* b2 = (const float*)d_in[6];
    const float* Wz = (const float*)d_in[7];
    const float* bz = (const float*)d_in[8];
    const float* Wr = (const float*)d_in[9];
    const float* br = (const float*)d_in[10];
    const float* Wc = (const float*)d_in[11];
    const float* bc = (const float*)d_in[12];
    float* out = (float*)d_out;

    int N = in_sizes[0] / 2;     // 100000
    int E = in_sizes[1] / 2;     // 1600000
    int NB = (N + 255) / 256;

    // workspace layout (u32 units):
    //   dinv N | row N | cnt N | txa 2N | txb 2N | bs 1024 | WT 18432
    //   | cntsc 2*NBN | scanned 2*NBN | srcw 2E
    //   O: bufA 32N | hpp 32N       (dstrec 2E | srckeys E alias [O, O+64N))
    char* wsb = (char*)d_ws;
    float* dinv = (float*)wsb;                                   // N
    int*   row  = (int*)  (wsb + (size_t)N * 4);                 // N
    int*   cnt  = (int*)  (wsb + (size_t)2 * N * 4);             // N
    float* txa  = (float*)(wsb + (size_t)3 * N * 4);             // 2N
    float* txb  = (float*)(wsb + (size_t)5 * N * 4);             // 2N
    int*   bs   = (int*)  (wsb + (size_t)7 * N * 4);             // 1024
    unsigned int* WT = (unsigned int*)(wsb + ((size_t)7 * N + 1024) * 4);      // 18432
    int*   cntsc   = (int*)(wsb + ((size_t)7 * N + 19456) * 4);                // 2*NBN
    int*   scanned = (int*)(wsb + ((size_t)7 * N + 19456 + 2 * NBN) * 4);      // 2*NBN
    int2*  srcw = (int2*)(wsb + ((size_t)7 * N + 19456 + 4 * NBN) * 4);        // 2E
    size_t O = (size_t)7 * N + 19456 + 4 * (size_t)NBN + 2 * (size_t)E;
    unsigned int* bufA = (unsigned int*)(wsb + O * 4);                         // 32N
    unsigned int* hpp  = (unsigned int*)(wsb + (O + (size_t)32 * N) * 4);      // 32N
    int2*  dstrec  = (int2*)(wsb + O * 4);                                     // 2E (alias)
    int*   srckeys = (int*) (wsb + (O + 2 * (size_t)E) * 4);                   // E  (alias)

    // ---- bucketed CSR build (no global atomics, no memset) ----
    bucketA_kernel<<<NBA, 256, 0, stream>>>(ei, E, cntsc);
    int scn = 2 * NBN;
    scanA_kernel<<<scn / 256, 256, 0, stream>>>(cntsc, bs, scn);
    scanB_kernel<<<1, 1024, 0, stream>>>(bs, scn / 256);
    scanC_kernel<<<scn / 256, 256, 0, stream>>>(cntsc, bs, scanned, scn);
    bucketB_kernel<<<NBA, 256, 0, stream>>>(ei, E, scanned, dstrec, srckeys);
    bucketC2_kernel<<<NBUCK, BINS, 0, stream>>>(srckeys, scanned, dinv, N, E);
    bucketC1_kernel<<<NBUCK, BINS, 0, stream>>>(dstrec, scanned, dinv, row, cnt, srcw, N, E);

    // packs (after C1/C2: hpp/bufA alias dstrec/srckeys)
    packwT_kernel<<<(18432 + 255) / 256, 256, 0, stream>>>(W2, Wz, Wr, Wc, WT);
    packh_kernel <<<(32 * N + 255) / 256, 256, 0, stream>>>(h, hpp, 32 * N);

    // input path: x -> txa -> txb (2 channels, gather)
    gather2_kernel<<<NB, 256, 0, stream>>>(row, cnt, srcw, dinv, x,   txa, N);
    gather2_kernel<<<NB, 256, 0, stream>>>(row, cnt, srcw, dinv, txa, txb, N);

    // hidden path: hbf -> bufA -> ppbf (monolithic bf16 rows; hpp dual-use)
    int gblocks = (N + 3) / 4;
    gather64_kernel<<<gblocks, 256, 0, stream>>>(row, cnt, srcw, dinv, hpp,  bufA, N);
    gather64_kernel<<<gblocks, 256, 0, stream>>>(row, cnt, srcw, dinv, bufA, hpp,  N);

    // fused MFMA gate (wave = 32 nodes, block = 128 nodes)
    int gateblocks = (N + 127) / 128;
    gate_mfma_kernel<<<gateblocks, 256, 0, stream>>>(
        out, x, h, txa, txb, bufA, hpp, W1, b1, WT, b2, bz, br, bc, N);
}